// Round 7
// baseline (919.230 us; speedup 1.0000x reference)
//
#include <hip/hip_runtime.h>
#include <math.h>

#define N_  100000
#define P_  96
#define V_  4
#define M_  70000
#define K_  43
#define KC_ 27

typedef unsigned short u16;
typedef __attribute__((ext_vector_type(8))) short bf16x8;
typedef __attribute__((ext_vector_type(4))) float f32x4;
typedef __attribute__((ext_vector_type(16))) float f32x16;

__device__ __forceinline__ u16 f2bf(float f) {
    unsigned int u = __float_as_uint(f);
    u += 0x7fffu + ((u >> 16) & 1u);   // round-to-nearest-even
    return (u16)(u >> 16);
}
__device__ __forceinline__ float bf2f(u16 h) {
    return __uint_as_float(((unsigned int)h) << 16);
}

// async global->LDS DMA, 16 B per lane; dest = wave-uniform base + lane*16
__device__ __forceinline__ void gl_lds16(const u16* g, u16* l) {
    __builtin_amdgcn_global_load_lds(
        (const __attribute__((address_space(1))) void*)g,
        (__attribute__((address_space(3))) void*)l, 16, 0, 0);
}

// ---------------------------------------------------------------------------
__global__ __launch_bounds__(256) void k_build_srcof(const int* __restrict__ km,
                                                     int* __restrict__ srcOf) {
    int idx = blockIdx.x * 256 + threadIdx.x;
    if (idx >= K_ * M_) return;
    int k = idx / M_;
    int e = idx - k * M_;
    const int* p = km + (size_t)(k * M_ + e) * 2;
    srcOf[(size_t)k * N_ + p[1]] = p[0];
}

// rowAbs[r] = sum_j |x[r][j]|  AND  xb = bf16(x), stride 96
__global__ __launch_bounds__(256) void k_rowabs_cvt(const float* __restrict__ x,
                                                    float* __restrict__ rowAbs,
                                                    u16* __restrict__ xb) {
    int row = blockIdx.x * 4 + (threadIdx.x >> 6);
    int lane = threadIdx.x & 63;
    if (row >= N_) return;
    const float* xr = x + (size_t)row * 96;
    float s = 0.f;
    for (int j = lane; j < 96; j += 64) {
        float v = xr[j];
        s += fabsf(v);
        xb[(size_t)row * 96 + j] = f2bf(v);
    }
#pragma unroll
    for (int o = 32; o > 0; o >>= 1) s += __shfl_down(s, o, 64);
    if (lane == 0) rowAbs[row] = s;
}

// Padded weight image for async staging: Wp[k*10240 + n*104 + j] = bf16(W[k][j][n])
__global__ __launch_bounds__(256) void k_wt96p(const float* __restrict__ W,
                                               u16* __restrict__ Wp) {
    int idx = blockIdx.x * 256 + threadIdx.x;
    if (idx >= KC_ * 96 * 96) return;
    int k = idx / 9216, rem = idx - k * 9216, n = rem / 96, j = rem - n * 96;
    Wp[(size_t)k * 10240 + n * 104 + j] = f2bf(W[(size_t)k * 9216 + j * 96 + n]);
}

// Bimg[n*104 + j] = bf16(Wq2[n/4][j][n&3]) for n<108,j<96 else 0  (128x104 image)
__global__ __launch_bounds__(256) void k_wtB(const float* __restrict__ W,
                                             u16* __restrict__ Bimg) {
    int idx = blockIdx.x * 256 + threadIdx.x;
    if (idx >= 128 * 104) return;
    int n = idx / 104, j = idx - n * 104;
    u16 v = 0;
    if (j < 96 && n < 108) {
        int ks = n >> 2, c = n & 3;
        v = f2bf(W[(size_t)ks * 384 + j * 4 + c]);
    }
    Bimg[idx] = v;
}

// w1b[j][c32] = bf16(W1[c][j]) c<4 else 0; w2b[n16][j] = bf16(W2[j][n]) n<4 else 0
__global__ __launch_bounds__(256) void k_w12b(const float* __restrict__ W1,
                                              const float* __restrict__ W2,
                                              u16* __restrict__ w1b,
                                              u16* __restrict__ w2b) {
    int t = blockIdx.x * 256 + threadIdx.x;
    if (t < 96 * 32) {
        int j = t >> 5, c = t & 31;
        w1b[t] = (c < 4) ? f2bf(W1[c * 96 + j]) : (u16)0;
    }
    if (t < 16 * 96) {
        int n = t / 96, j = t - n * 96;
        w2b[t] = (n < 4) ? f2bf(W2[j * 4 + n]) : (u16)0;
    }
}

// ---------------------------------------------------------------------------
// Dual conv, 32x32x16 MFMA, 192 rows/block, 384 threads (6 waves) — proven
// R0 structure (L3-random-line bound; lowest line count of variants tried).
__global__ __launch_bounds__(384, 3) void k_conv96_dual(
    const u16* __restrict__ xb, const u16* __restrict__ Wqp,
    const u16* __restrict__ Wvp, const int* __restrict__ srcOf,
    u16* __restrict__ yQ, u16* __restrict__ yV,
    float* __restrict__ statsQ, float* __restrict__ statsV) {
    __shared__ u16 sA[192 * 104];   // 39,936 B
    __shared__ u16 sBq[10240];      // 20,480 B (96x104 padded image)
    __shared__ u16 sBv[10240];      // 20,480 B
    const int r0 = blockIdx.x * 192;
    const int t = threadIdx.x;
    const int wv = t / 64, lane = t & 63;
    const int n32 = lane & 31, half = lane >> 5;
    const int ea = t >> 1, jca = (t & 1) * 6;
    f32x16 accq[3], accv[3];
#pragma unroll
    for (int i = 0; i < 3; i++) {
#pragma unroll
        for (int j = 0; j < 16; j++) { accq[i][j] = 0.f; accv[i][j] = 0.f; }
    }

    for (int k = 0; k < KC_; k++) {
        __syncthreads();
        {
            const u16* gq = Wqp + (size_t)k * 10240;
            const u16* gv = Wvp + (size_t)k * 10240;
            for (int i = wv; i < 40; i += 6) {
                int mv = (i >= 20);
                int off = (mv ? i - 20 : i) * 512 + lane * 8;
                gl_lds16((mv ? gv : gq) + off, (mv ? (u16*)sBv : (u16*)sBq) + off);
            }
        }
        {
            int r = r0 + ea;
            int src = (r < N_) ? srcOf[(size_t)k * N_ + r] : -1;
            if (src >= 0) {
                const uint4* sp = (const uint4*)(xb + (size_t)src * 96);
#pragma unroll
                for (int i = 0; i < 6; i++)
                    *(uint4*)(sA + ea * 104 + (jca + i) * 8) = sp[jca + i];
            } else {
                uint4 z = make_uint4(0, 0, 0, 0);
#pragma unroll
                for (int i = 0; i < 6; i++)
                    *(uint4*)(sA + ea * 104 + (jca + i) * 8) = z;
            }
        }
        __syncthreads();   // drains vmcnt (DMA) + lgkmcnt (ds_write)
#pragma unroll
        for (int ks = 0; ks < 6; ks++) {
            bf16x8 af = *(const bf16x8*)(sA + (wv * 32 + n32) * 104 + ks * 16 + half * 8);
#pragma unroll
            for (int nt = 0; nt < 3; nt++) {
                bf16x8 bq = *(const bf16x8*)(sBq + (nt * 32 + n32) * 104 + ks * 16 + half * 8);
                accq[nt] = __builtin_amdgcn_mfma_f32_32x32x16_bf16(af, bq, accq[nt], 0, 0, 0);
                bf16x8 bv = *(const bf16x8*)(sBv + (nt * 32 + n32) * 104 + ks * 16 + half * 8);
                accv[nt] = __builtin_amdgcn_mfma_f32_32x32x16_bf16(af, bv, accv[nt], 0, 0, 0);
            }
        }
    }
#pragma unroll
    for (int nt = 0; nt < 3; nt++) {
#pragma unroll
        for (int reg = 0; reg < 16; reg++) {
            int row = (reg & 3) + 8 * (reg >> 2) + 4 * half;
            int r = r0 + wv * 32 + row;
            if (r < N_) {
                yQ[(size_t)r * 96 + nt * 32 + n32] = f2bf(accq[nt][reg]);
                yV[(size_t)r * 96 + nt * 32 + n32] = f2bf(accv[nt][reg]);
            }
        }
    }
    __syncthreads();
    float* sred = (float*)sA;
    for (int pass = 0; pass < 2; pass++) {
        f32x16* acc = pass ? accv : accq;
        float* st = pass ? statsV : statsQ;
#pragma unroll
        for (int nt = 0; nt < 3; nt++) {
            float sv = 0.f, qv = 0.f;
#pragma unroll
            for (int reg = 0; reg < 16; reg++) {
                float a = acc[nt][reg];
                sv += a; qv += a * a;
            }
            sv += __shfl_xor(sv, 32, 64);
            qv += __shfl_xor(qv, 32, 64);
            if (half == 0) {
                sred[wv * 192 + nt * 32 + n32] = sv;
                sred[wv * 192 + 96 + nt * 32 + n32] = qv;
            }
        }
        __syncthreads();
        if (t < 192) {
            float tot = 0.f;
#pragma unroll
            for (int w = 0; w < 6; w++) tot += sred[w * 192 + t];
            atomicAdd(&st[t], tot);
        }
        __syncthreads();
    }
}

// Dense projection: g[r][n] = (relu(bn(yQ[r])) @ Wq2all)[n], n = k*4+c, n<108.
__global__ __launch_bounds__(256) void k_proj(
    const u16* __restrict__ xq, const float* __restrict__ stats,
    const float* __restrict__ gg, const float* __restrict__ bb,
    const u16* __restrict__ Bimg, u16* __restrict__ gout) {
    __shared__ u16 sA[128 * 104];
    __shared__ u16 sB[128 * 104];
    __shared__ float sSc[96], sSh[96];
    const int r0 = blockIdx.x * 128;
    const int t = threadIdx.x;
    const int wv = t >> 6, lane = t & 63;
    const int n32 = lane & 31, half = lane >> 5;
    if (t < 96) {
        float mean = stats[t] * (1.f / N_);
        float var = stats[96 + t] * (1.f / N_) - mean * mean;
        float sc = gg[t] * rsqrtf(fmaxf(var, 0.f) + 1e-5f);
        sSc[t] = sc; sSh[t] = bb[t] - mean * sc;
    }
    for (int i = t; i < 1664; i += 256)
        ((uint4*)sB)[i] = ((const uint4*)Bimg)[i];
    __syncthreads();
    {
        int ea = t >> 1, jca = (t & 1) * 6;
        int r = r0 + ea;
        bool ok = (r < N_);
        const u16* xr = xq + (size_t)(ok ? r : 0) * 96;
#pragma unroll
        for (int i = 0; i < 6; i++) {
            int cb = (jca + i) * 8;
            uint4 v = ok ? *(const uint4*)(xr + cb) : make_uint4(0, 0, 0, 0);
            const u16* pv = (const u16*)&v;
            u16 o[8];
#pragma unroll
            for (int e = 0; e < 8; e++) {
                float h = bf2f(pv[e]);
                h = fmaxf(h * sSc[cb + e] + sSh[cb + e], 0.f);
                o[e] = f2bf(h);
            }
            *(uint4*)(sA + ea * 104 + cb) = *(uint4*)o;
        }
    }
    __syncthreads();
    f32x16 acc[4];
#pragma unroll
    for (int i = 0; i < 4; i++)
#pragma unroll
        for (int j = 0; j < 16; j++) acc[i][j] = 0.f;
#pragma unroll
    for (int ks = 0; ks < 6; ks++) {
        bf16x8 af = *(const bf16x8*)(sA + (wv * 32 + n32) * 104 + ks * 16 + half * 8);
#pragma unroll
        for (int nt = 0; nt < 4; nt++) {
            bf16x8 bf = *(const bf16x8*)(sB + (nt * 32 + n32) * 104 + ks * 16 + half * 8);
            acc[nt] = __builtin_amdgcn_mfma_f32_32x32x16_bf16(af, bf, acc[nt], 0, 0, 0);
        }
    }
#pragma unroll
    for (int nt = 0; nt < 4; nt++) {
        int col = nt * 32 + n32;
        if (col < 108) {
#pragma unroll
            for (int reg = 0; reg < 16; reg++) {
                int row = (reg & 3) + 8 * (reg >> 2) + 4 * half;
                int r = r0 + wv * 32 + row;
                if (r < N_) gout[(size_t)r * 108 + col] = f2bf(acc[nt][reg]);
            }
        }
    }
}

// qf[r][c] = sum_k g[srcOf[k][r]][k*4+c]  — MLP-batched (9 k's in flight)
__global__ __launch_bounds__(256) void k_gather4(
    const u16* __restrict__ g, const int* __restrict__ srcOf,
    float* __restrict__ qf) {
    int idx = blockIdx.x * 256 + threadIdx.x;
    if (idx >= N_ * 4) return;
    int r = idx >> 2, c = idx & 3;
    float a = 0.f;
    int sv[9]; u16 gv[9];
#pragma unroll 1
    for (int kb = 0; kb < 27; kb += 9) {
#pragma unroll
        for (int j = 0; j < 9; j++)
            sv[j] = srcOf[(size_t)(kb + j) * N_ + r];
#pragma unroll
        for (int j = 0; j < 9; j++) {
            int sc = (sv[j] >= 0) ? sv[j] : 0;
            gv[j] = g[(size_t)sc * 108 + (kb + j) * 4 + c];
        }
#pragma unroll
        for (int j = 0; j < 9; j++)
            if (sv[j] >= 0) a += bf2f(gv[j]);
    }
    qf[idx] = a;
}

// ---------------------------------------------------------------------------
__global__ __launch_bounds__(192) void k_bnstats96(const float* __restrict__ xin,
                                                   float* __restrict__ stats) {
    __shared__ float sS[192], sQ[192];
    int t = threadIdx.x;
    int ch = t % 96, half = t / 96;
    float s = 0.f, q = 0.f;
    for (int r = blockIdx.x * 2 + half; r < N_; r += gridDim.x * 2) {
        float v = xin[(size_t)r * 96 + ch];
        s += v; q += v * v;
    }
    sS[t] = s; sQ[t] = q;
    __syncthreads();
    if (t < 96) {
        atomicAdd(&stats[ch], sS[t] + sS[t + 96]);
        atomicAdd(&stats[96 + ch], sQ[t] + sQ[t + 96]);
    }
}

__global__ __launch_bounds__(256) void k_bnstats4(const float* __restrict__ xin,
                                                  float* __restrict__ stats) {
    __shared__ float sS[256], sQ[256];
    int t = threadIdx.x;
    int c = t & 3, sub = t >> 2;
    float s = 0.f, q = 0.f;
    for (int r = blockIdx.x * 64 + sub; r < N_; r += gridDim.x * 64) {
        float v = xin[(size_t)r * 4 + c];
        s += v; q += v * v;
    }
    sS[t] = s; sQ[t] = q;
    __syncthreads();
    for (int off = 128; off >= 4; off >>= 1) {
        if (t < off) { sS[t] += sS[t + off]; sQ[t] += sQ[t + off]; }
        __syncthreads();
    }
    if (t < 4) {
        atomicAdd(&stats[t], sS[t]);
        atomicAdd(&stats[96 + t], sQ[t]);
    }
}

// f32 in/out (MODE 0: relu(bn)  MODE 2: relu(bn)+aux)
template <int C, int MODE>
__global__ __launch_bounds__(256) void k_bnapply(float* __restrict__ y,
                                                 const float* __restrict__ stats,
                                                 const float* __restrict__ g,
                                                 const float* __restrict__ b,
                                                 const float* __restrict__ aux) {
    int idx = blockIdx.x * 256 + threadIdx.x;
    if (idx >= N_ * C) return;
    int ch = idx % C;
    float mean = stats[ch] * (1.f / N_);
    float var = stats[96 + ch] * (1.f / N_) - mean * mean;
    float scale = g[ch] * rsqrtf(fmaxf(var, 0.f) + 1e-5f);
    float v = (y[idx] - mean) * scale + b[ch];
    v = fmaxf(v, 0.f);
    if (MODE == 2) v += aux[idx];
    y[idx] = v;
}

// bf16 in -> bf16 out, C=96, relu(bn) + relu(bn(peRAW)) repeat.
// peb is RAW pe2 output; its bn (statsP, gp2, bp2) applied inline.
__global__ __launch_bounds__(256) void k_bnapply96_pe(
    const u16* __restrict__ yin, const float* __restrict__ stats,
    const float* __restrict__ g, const float* __restrict__ b,
    const float* __restrict__ aux, const float* __restrict__ statsP,
    const float* __restrict__ gp2, const float* __restrict__ bp2,
    u16* __restrict__ yout) {
    int idx = blockIdx.x * 256 + threadIdx.x;
    if (idx >= N_ * 96) return;
    int ch = idx % 96;
    float mean = stats[ch] * (1.f / N_);
    float var = stats[96 + ch] * (1.f / N_) - mean * mean;
    float scale = g[ch] * rsqrtf(fmaxf(var, 0.f) + 1e-5f);
    float v = (bf2f(yin[idx]) - mean) * scale + b[ch];
    v = fmaxf(v, 0.f);
    int r = idx / 96;
    int c = ch / 24;
    float pm = statsP[c] * (1.f / N_);
    float pv = statsP[96 + c] * (1.f / N_) - pm * pm;
    float psc = gp2[c] * rsqrtf(fmaxf(pv, 0.f) + 1e-5f);
    float pe = fmaxf(aux[(size_t)r * 4 + c] * psc + (bp2[c] - pm * psc), 0.f);
    yout[idx] = f2bf(v + pe);
}

// pe1 fused with its BN stats: h = coords @ Wp1 (bf16 out) + per-ch sum/sumsq
__global__ __launch_bounds__(192) void k_pe1s(const float* __restrict__ coords,
                                              const float* __restrict__ Wp1,
                                              u16* __restrict__ out,
                                              float* __restrict__ stats) {
    __shared__ float sS[192], sQ[192];
    int t = threadIdx.x;
    int ch = t % 96, half = t / 96;
    float w0 = Wp1[ch], w1 = Wp1[96 + ch], w2 = Wp1[192 + ch];
    float s = 0.f, q = 0.f;
    for (int r = blockIdx.x * 2 + half; r < N_; r += gridDim.x * 2) {
        float c0 = coords[r * 3], c1 = coords[r * 3 + 1], c2 = coords[r * 3 + 2];
        float v = c0 * w0 + c1 * w1 + c2 * w2;
        out[(size_t)r * 96 + ch] = f2bf(v);
        s += v; q += v * v;
    }
    sS[t] = s; sQ[t] = q;
    __syncthreads();
    if (t < 96) {
        atomicAdd(&stats[ch], sS[t] + sS[t + 96]);
        atomicAdd(&stats[96 + ch], sQ[t] + sQ[t + 96]);
    }
}

// pe2 with inline bn+relu of h1 (raw pe2 output; its own bn applied downstream)
__global__ __launch_bounds__(256) void k_pe2b(const u16* __restrict__ hin,
                                              const float* __restrict__ stats,
                                              const float* __restrict__ gp,
                                              const float* __restrict__ bp,
                                              const float* __restrict__ Wp2,
                                              float* __restrict__ out) {
    __shared__ float sSc[96], sSh[96], sW[384];
    int t = threadIdx.x;
    if (t < 96) {
        float mean = stats[t] * (1.f / N_);
        float var = stats[96 + t] * (1.f / N_) - mean * mean;
        float sc = gp[t] * rsqrtf(fmaxf(var, 0.f) + 1e-5f);
        sSc[t] = sc; sSh[t] = bp[t] - mean * sc;
    }
    for (int i = t; i < 384; i += 256) sW[i] = Wp2[i];
    __syncthreads();
    int idx = blockIdx.x * 256 + t;
    if (idx >= N_ * 4) return;
    int r = idx >> 2, c = idx & 3;
    const u16* hr = hin + (size_t)r * 96;
    float acc = 0.f;
#pragma unroll 4
    for (int j = 0; j < 96; j++) {
        float h = fmaxf(bf2f(hr[j]) * sSc[j] + sSh[j], 0.f);
        acc += h * sW[j * 4 + c];
    }
    out[idx] = acc;
}

// ---------------------------------------------------------------------------
// FUSED attention: MFMA logits (32 rows/block) + in-LDS softmax + weighted
// gather of vfb, writing `out` directly (wbuf eliminated). qf is RAW
// gather4 output; its bn+relu (statsQ, gq2, bq2) is applied inline.
__global__ __launch_bounds__(256) void k_attn_fused(
    const float* __restrict__ qf, const int* __restrict__ srcOf,
    const float* __restrict__ rowAbs,
    const u16* __restrict__ w1b, const float* __restrict__ b1,
    const u16* __restrict__ w2b, const float* __restrict__ b2,
    const float* __restrict__ statsQ, const float* __restrict__ gq2,
    const float* __restrict__ bq2,
    const u16* __restrict__ vfb, float* __restrict__ out) {
    __shared__ u16 hbuf[4][16 * 104];
    __shared__ u16 slogb[32][176];
    __shared__ u16 smk16[32][44];
    const int t = threadIdx.x;
    const int wv = t >> 6, lane = t & 63;
    const int col = lane & 15, quad = lane >> 4;
    const int r0 = blockIdx.x * 32;

    float qsc[4], qsh[4];
#pragma unroll
    for (int c = 0; c < 4; c++) {
        float mean = statsQ[c] * (1.f / N_);
        float var = statsQ[96 + c] * (1.f / N_) - mean * mean;
        float s = gq2[c] * rsqrtf(fmaxf(var, 0.f) + 1e-5f);
        qsc[c] = s; qsh[c] = bq2[c] - mean * s;
    }

    bf16x8 w1f[6];
    float b1v[6];
#pragma unroll
    for (int nt = 0; nt < 6; nt++) {
        w1f[nt] = *(const bf16x8*)(w1b + (nt * 16 + col) * 32 + quad * 8);
        b1v[nt] = b1[nt * 16 + col];
    }
    bf16x8 w2f[3];
#pragma unroll
    for (int kk = 0; kk < 3; kk++)
        w2f[kk] = *(const bf16x8*)(w2b + col * 96 + kk * 32 + quad * 8);
    float b2v = b2[col & 3];

    u16* hb = hbuf[wv];
    for (int tt = 0; tt < 22; tt++) {
        int tileBase = (wv * 22 + tt) * 16;
        bf16x8 af = (bf16x8){0, 0, 0, 0, 0, 0, 0, 0};
        if (quad == 0) {
            int P = tileBase + col;
            int rL = P / 44, k = P - rL * 44;
            int kc = (k < 43) ? k : 42;
            int r = r0 + rL;
            int s = srcOf[(size_t)kc * N_ + r];
            if (k == 43) s = -1;
            int sc = (s >= 0) ? s : 0;
            float mk = (s >= 0 && rowAbs[sc] > 0.f) ? 1.f : 0.f;
            float4 qs = *(const float4*)(qf + (size_t)sc * 4);
            float4 qr = *(const float4*)(qf + (size_t)r * 4);
            qs.x = fmaxf(qs.x * qsc[0] + qsh[0], 0.f);
            qs.y = fmaxf(qs.y * qsc[1] + qsh[1], 0.f);
            qs.z = fmaxf(qs.z * qsc[2] + qsh[2], 0.f);
            qs.w = fmaxf(qs.w * qsc[3] + qsh[3], 0.f);
            qr.x = fmaxf(qr.x * qsc[0] + qsh[0], 0.f);
            qr.y = fmaxf(qr.y * qsc[1] + qsh[1], 0.f);
            qr.z = fmaxf(qr.z * qsc[2] + qsh[2], 0.f);
            qr.w = fmaxf(qr.w * qsc[3] + qsh[3], 0.f);
            af[0] = (short)f2bf((qs.x - qr.x) * mk);
            af[1] = (short)f2bf((qs.y - qr.y) * mk);
            af[2] = (short)f2bf((qs.z - qr.z) * mk);
            af[3] = (short)f2bf((qs.w - qr.w) * mk);
            if (k < 43) smk16[rL][k] = (u16)(mk > 0.f ? 1 : 0);
        }
        f32x4 c1[6];
#pragma unroll
        for (int nt = 0; nt < 6; nt++) {
            c1[nt] = (f32x4){0.f, 0.f, 0.f, 0.f};
            c1[nt] = __builtin_amdgcn_mfma_f32_16x16x32_bf16(af, w1f[nt], c1[nt], 0, 0, 0);
        }
#pragma unroll
        for (int nt = 0; nt < 6; nt++) {
#pragma unroll
            for (int rg = 0; rg < 4; rg++) {
                float h = fmaxf(c1[nt][rg] + b1v[nt], 0.f);
                hb[(quad * 4 + rg) * 104 + nt * 16 + col] = f2bf(h);
            }
        }
        f32x4 acc2 = (f32x4){0.f, 0.f, 0.f, 0.f};
#pragma unroll
        for (int kk = 0; kk < 3; kk++) {
            bf16x8 a2 = *(const bf16x8*)(hb + col * 104 + kk * 32 + quad * 8);
            acc2 = __builtin_amdgcn_mfma_f32_16x16x32_bf16(a2, w2f[kk], acc2, 0, 0, 0);
        }
        if (col < 4) {
#pragma unroll
            for (int rg = 0; rg < 4; rg++) {
                int P = tileBase + quad * 4 + rg;
                int rL = P / 44, k = P - rL * 44;
                if (k < 43) {
                    float mval = (float)smk16[rL][k];
                    slogb[rL][k * 4 + col] = f2bf((acc2[rg] + b2v) * mval);
                }
            }
        }
    }
    __syncthreads();

    if (t < 128) {
        int rL = t >> 2, c = t & 3;
        float mx = 0.f;
        for (int k = 0; k < K_; k++) mx = fmaxf(mx, bf2f(slogb[rL][k * 4 + c]));
        float den = 0.f;
        for (int k = 0; k < K_; k++) den += __expf(bf2f(slogb[rL][k * 4 + c]) - mx);
        float inv = 1.f / den;
        for (int k = 0; k < K_; k++)
            slogb[rL][k * 4 + c] = f2bf(__expf(bf2f(slogb[rL][k * 4 + c]) - mx) * inv);
    }
    __syncthreads();

    // --- gather phase: 3 passes over (rL, c4); MLP-batched 8-deep
#pragma unroll 1
    for (int pass = 0; pass < 3; pass++) {
        int p = pass * 256 + t;          // 0..767
        int rL = p / 24, c4 = p - rL * 24;
        int r = r0 + rL;
        int cg = c4 / 6;
        float a0 = 0.f, a1 = 0.f, a2 = 0.f, a3 = 0.f;
        int sv[8]; float wv8[8]; ushort4 vv[8];
#pragma unroll 1
        for (int kb = 0; kb < 40; kb += 8) {
#pragma unroll
            for (int j = 0; j < 8; j++)
                sv[j] = srcOf[(size_t)(kb + j) * N_ + r];
#pragma unroll
            for (int j = 0; j < 8; j++) {
                int k = kb + j;
                int idxk = (k < 27) ? k : ((k < 35) ? (k - 27) : (k - 35));
                wv8[j] = smk16[rL][k] ? bf2f(slogb[rL][idxk * 4 + cg]) : 0.f;
            }
#pragma unroll
            for (int j = 0; j < 8; j++) {
                int sc = (sv[j] >= 0) ? sv[j] : 0;
                vv[j] = *(const ushort4*)(vfb + (size_t)sc * 96 + c4 * 4);
            }
#pragma unroll
            for (int j = 0; j < 8; j++) {
                float w = wv8[j];
                a0 += w * bf2f(vv[j].x);
                a1 += w * bf2f(vv[j].y);
                a2 += w * bf2f(vv[j].z);
                a3 += w * bf2f(vv[j].w);
            }
        }
#pragma unroll
        for (int j = 0; j < 3; j++)
            sv[j] = srcOf[(size_t)(40 + j) * N_ + r];
#pragma unroll
        for (int j = 0; j < 3; j++) {
            int k = 40 + j;
            wv8[j] = smk16[rL][k] ? bf2f(slogb[rL][(k - 35) * 4 + cg]) : 0.f;
        }
#pragma unroll
        for (int j = 0; j < 3; j++) {
            int sc = (sv[j] >= 0) ? sv[j] : 0;
            vv[j] = *(const ushort4*)(vfb + (size_t)sc * 96 + c4 * 4);
        }
#pragma unroll
        for (int j = 0; j < 3; j++) {
            float w = wv8[j];
            a0 += w * bf2f(vv[j].x);
            a1 += w * bf2f(vv[j].y);
            a2 += w * bf2f(vv[j].z);
            a3 += w * bf2f(vv[j].w);
        }
        *(float4*)(out + (size_t)r * 96 + c4 * 4) = make_float4(a0, a1, a2, a3);
    }
}

// ---------------------------------------------------------------------------
extern "C" void kernel_launch(void* const* d_in, const int* in_sizes, int n_in,
                              void* d_out, int out_size, void* d_ws, size_t ws_size,
                              hipStream_t stream) {
    const float* x      = (const float*)d_in[0];
    const float* coords = (const float*)d_in[1];
    const float* Wq1 = (const float*)d_in[2];
    const float* gq1 = (const float*)d_in[3];
    const float* bq1 = (const float*)d_in[4];
    const float* Wq2 = (const float*)d_in[5];
    const float* gq2 = (const float*)d_in[6];
    const float* bq2 = (const float*)d_in[7];
    const float* Wv  = (const float*)d_in[8];
    const float* gv  = (const float*)d_in[9];
    const float* bv  = (const float*)d_in[10];
    const float* Wp1 = (const float*)d_in[11];
    const float* gp1 = (const float*)d_in[12];
    const float* bp1 = (const float*)d_in[13];
    const float* Wp2 = (const float*)d_in[14];
    const float* gp2 = (const float*)d_in[15];
    const float* bp2 = (const float*)d_in[16];
    const float* W1  = (const float*)d_in[17];
    const float* b1  = (const float*)d_in[18];
    const float* W2  = (const float*)d_in[19];
    const float* b2  = (const float*)d_in[20];
    const float* g_out = (const float*)d_in[21];
    const float* b_out = (const float*)d_in[22];
    const int* kmaps = (const int*)d_in[23];
    float* out = (float*)d_out;

    // ---- workspace map ----
    char* ws = (char*)d_ws;
    int*   srcOf  = (int*)ws;                     //  0.0-17.2M  P1-P8
    float* rowAbs = (float*)(ws + 17200000);      // 17.2-17.6M  P1-P7
    u16*   xb     = (u16*)(ws + 17600000);        // 17.6-36.8M  P1-P2
    u16*   pescr  = (u16*)(ws + 17600000);        //   overlays xb      P5 (bf16)
    u16*   bufQb  = (u16*)(ws + 36800000);        // 36.8-56.0M  P2-P3
    float* peb    = (float*)(ws + 36800000);      //   overlays bufQb   P5-P6
    u16*   Wq1p   = (u16*)(ws + 56000000);        // 56.0-56.55M P1-P2
    u16*   Wvp    = (u16*)(ws + 56552960);        // 56.55-57.1M P1-P2
    u16*   gbuf   = (u16*)(ws + 56000000);        //   56.0-77.6M      P3-P4
    u16*   vfb    = (u16*)(ws + 56000000);        //   56.0-75.2M      P6-P8
    u16*   bufVb  = (u16*)(ws + 77600000);        // 77.6-96.8M  P2-P6
    u16*   Bimg   = (u16*)(ws + 96800000);        // 96.8M+26KB  P1-P3
    float* qf     = (float*)(ws + 96800000);      //   96.8-98.4M      P4-P7 (overlays Bimg)
    u16*   w1b    = (u16*)(ws + 98400000);        //              P1-P7
    u16*   w2b    = (u16*)(ws + 98406144);
    float* stats  = (float*)(ws + 98409216);      // 6*192 floats

    hipMemsetAsync(srcOf, 0xFF, (size_t)K_ * N_ * 4, stream);  // -1
    hipMemsetAsync(stats, 0, 6 * 192 * 4, stream);

    k_build_srcof<<<(K_ * M_ + 255) / 256, 256, 0, stream>>>(kmaps, srcOf);
    k_rowabs_cvt<<<N_ / 4, 256, 0, stream>>>(x, rowAbs, xb);
    k_wt96p<<<(KC_ * 9216 + 255) / 256, 256, 0, stream>>>(Wq1, Wq1p);
    k_wt96p<<<(KC_ * 9216 + 255) / 256, 256, 0, stream>>>(Wv, Wvp);
    k_wtB<<<52, 256, 0, stream>>>(Wq2, Bimg);
    k_w12b<<<12, 256, 0, stream>>>(W1, W2, w1b, w2b);

    const int cbD  = (N_ + 191) / 192;   // 521
    const int eb96 = N_ * 96 / 256;      // 37500
    const int eb4  = (N_ * 4 + 255) / 256;

    // P2: both convs + their BN stats in one pass
    k_conv96_dual<<<cbD, 384, 0, stream>>>(xb, Wq1p, Wvp, srcOf, bufQb, bufVb,
                                           stats + 0 * 192, stats + 4 * 192);

    // P3/P4: q-branch: dense projection (bn inline) -> 8B gather -> stats
    // (qf stays RAW; its bn+relu is applied inline in k_attn_fused)
    k_proj<<<(N_ + 127) / 128, 256, 0, stream>>>(bufQb, stats + 0 * 192, gq1, bq1,
                                                 Bimg, gbuf);
    k_gather4<<<eb4, 256, 0, stream>>>(gbuf, srcOf, qf);
    k_bnstats4<<<512, 256, 0, stream>>>(qf, stats + 1 * 192);

    // P5: pe chain (pe1+stats fused; pe2 with inline bn of h1; peb stays RAW,
    // its bn+relu applied inline in k_bnapply96_pe)
    k_pe1s<<<512, 192, 0, stream>>>(coords, Wp1, pescr, stats + 2 * 192);
    k_pe2b<<<eb4, 256, 0, stream>>>(pescr, stats + 2 * 192, gp1, bp1, Wp2, peb);
    k_bnstats4<<<512, 256, 0, stream>>>(peb, stats + 3 * 192);

    // P6: v-branch: bn+relu + relu(bn(peb)) -> vfb
    k_bnapply96_pe<<<eb96, 256, 0, stream>>>(bufVb, stats + 4 * 192, gv, bv, peb,
                                             stats + 3 * 192, gp2, bp2, vfb);

    // P7: fused attention (logits + softmax + gather, wbuf eliminated)
    k_attn_fused<<<N_ / 32, 256, 0, stream>>>(qf, srcOf, rowAbs, w1b, b1, w2b, b2,
                                              stats + 1 * 192, gq2, bq2, vfb, out);

    // P9: out = relu(bn(out)) + x
    k_bnstats96<<<512, 192, 0, stream>>>(out, stats + 5 * 192);
    k_bnapply<96, 2><<<eb96, 256, 0, stream>>>(out, stats + 5 * 192, g_out, b_out, x);
}

// Round 9
// 912.405 us; speedup vs baseline: 1.0075x; 1.0075x over previous
//
#include <hip/hip_runtime.h>
#include <math.h>

#define N_  100000
#define P_  96
#define V_  4
#define M_  70000
#define K_  43
#define KC_ 27

typedef unsigned short u16;
typedef unsigned char u8;
typedef __attribute__((ext_vector_type(8))) short bf16x8;
typedef __attribute__((ext_vector_type(4))) float f32x4;
typedef __attribute__((ext_vector_type(16))) float f32x16;

__device__ __forceinline__ u16 f2bf(float f) {
    unsigned int u = __float_as_uint(f);
    u += 0x7fffu + ((u >> 16) & 1u);   // round-to-nearest-even
    return (u16)(u >> 16);
}
__device__ __forceinline__ float bf2f(u16 h) {
    return __uint_as_float(((unsigned int)h) << 16);
}

// async global->LDS DMA, 16 B per lane; dest = wave-uniform base + lane*16
__device__ __forceinline__ void gl_lds16(const u16* g, u16* l) {
    __builtin_amdgcn_global_load_lds(
        (const __attribute__((address_space(1))) void*)g,
        (__attribute__((address_space(3))) void*)l, 16, 0, 0);
}

// ---------------------------------------------------------------------------
__global__ __launch_bounds__(256) void k_build_srcof(const int* __restrict__ km,
                                                     int* __restrict__ srcOf) {
    int idx = blockIdx.x * 256 + threadIdx.x;
    if (idx >= K_ * M_) return;
    int k = idx / M_;
    int e = idx - k * M_;
    const int* p = km + (size_t)(k * M_ + e) * 2;
    srcOf[(size_t)k * N_ + p[1]] = p[0];
}

// rowAbs[r] = sum|x[r]|  AND  xq8 = row-scaled int8(x), 128B rows:
// bytes 0..95 = int8 q (q = round(x*127/rowmax)), bytes 96..99 = float scale.
__global__ __launch_bounds__(256) void k_rowabs_cvti8(const float* __restrict__ x,
                                                      float* __restrict__ rowAbs,
                                                      u8* __restrict__ xq8) {
    int row = blockIdx.x * 4 + (threadIdx.x >> 6);
    int lane = threadIdx.x & 63;
    if (row >= N_) return;
    const float* xr = x + (size_t)row * 96;
    float v0 = xr[lane < 96 ? lane : 0];
    if (lane >= 96) v0 = 0.f;                 // (lane<64 always true; keep safe)
    float v1 = (lane + 64 < 96) ? xr[lane + 64] : 0.f;
    float s = fabsf(v0) + fabsf(v1);
    float m = fmaxf(fabsf(v0), fabsf(v1));
#pragma unroll
    for (int o = 32; o > 0; o >>= 1) {
        s += __shfl_down(s, o, 64);
        m = fmaxf(m, __shfl_xor(m, o, 64));   // all lanes end with row max
    }
    if (lane == 0) rowAbs[row] = s;
    float inv = (m > 0.f) ? 127.f / m : 0.f;
    u8* orow = xq8 + (size_t)row * 128;
    orow[lane] = (u8)(signed char)(int)rintf(v0 * inv);
    if (lane + 64 < 96) orow[lane + 64] = (u8)(signed char)(int)rintf(v1 * inv);
    if (lane == 0) *(float*)(orow + 96) = (m > 0.f) ? m * (1.f / 127.f) : 0.f;
}

// Padded weight image for async staging: Wp[k*10240 + n*104 + j] = bf16(W[k][j][n])
__global__ __launch_bounds__(256) void k_wt96p(const float* __restrict__ W,
                                               u16* __restrict__ Wp) {
    int idx = blockIdx.x * 256 + threadIdx.x;
    if (idx >= KC_ * 96 * 96) return;
    int k = idx / 9216, rem = idx - k * 9216, n = rem / 96, j = rem - n * 96;
    Wp[(size_t)k * 10240 + n * 104 + j] = f2bf(W[(size_t)k * 9216 + j * 96 + n]);
}

// Bimg[n*104 + j] = bf16(Wq2[n/4][j][n&3]) for n<108,j<96 else 0  (128x104 image)
__global__ __launch_bounds__(256) void k_wtB(const float* __restrict__ W,
                                             u16* __restrict__ Bimg) {
    int idx = blockIdx.x * 256 + threadIdx.x;
    if (idx >= 128 * 104) return;
    int n = idx / 104, j = idx - n * 104;
    u16 v = 0;
    if (j < 96 && n < 108) {
        int ks = n >> 2, c = n & 3;
        v = f2bf(W[(size_t)ks * 384 + j * 4 + c]);
    }
    Bimg[idx] = v;
}

// w1b[j][c32] = bf16(W1[c][j]) c<4 else 0; w2b[n16][j] = bf16(W2[j][n]) n<4 else 0
__global__ __launch_bounds__(256) void k_w12b(const float* __restrict__ W1,
                                              const float* __restrict__ W2,
                                              u16* __restrict__ w1b,
                                              u16* __restrict__ w2b) {
    int t = blockIdx.x * 256 + threadIdx.x;
    if (t < 96 * 32) {
        int j = t >> 5, c = t & 31;
        w1b[t] = (c < 4) ? f2bf(W1[c * 96 + j]) : (u16)0;
    }
    if (t < 16 * 96) {
        int n = t / 96, j = t - n * 96;
        w2b[t] = (n < 4) ? f2bf(W2[j * 4 + n]) : (u16)0;
    }
}

// ---------------------------------------------------------------------------
// Dual conv, 32x32x16 MFMA, 192 rows/block, 384 threads — proven R0 structure.
// A-gather: row-scaled int8 rows (128B = EXACTLY 1 line per row, was 2);
// decoded to bf16 inline during LDS staging (hidden under gather stall).
__global__ __launch_bounds__(384, 3) void k_conv96_dual(
    const u8* __restrict__ xq8, const u16* __restrict__ Wqp,
    const u16* __restrict__ Wvp, const int* __restrict__ srcOf,
    u16* __restrict__ yQ, u16* __restrict__ yV,
    float* __restrict__ statsQ, float* __restrict__ statsV) {
    __shared__ u16 sA[192 * 104];   // 39,936 B
    __shared__ u16 sBq[10240];      // 20,480 B (96x104 padded image)
    __shared__ u16 sBv[10240];      // 20,480 B
    const int r0 = blockIdx.x * 192;
    const int t = threadIdx.x;
    const int wv = t / 64, lane = t & 63;
    const int n32 = lane & 31, half = lane >> 5;
    const int ea = t >> 1, jb = (t & 1) * 48;   // 48 channels per thread
    f32x16 accq[3], accv[3];
#pragma unroll
    for (int i = 0; i < 3; i++) {
#pragma unroll
        for (int j = 0; j < 16; j++) { accq[i][j] = 0.f; accv[i][j] = 0.f; }
    }

    for (int k = 0; k < KC_; k++) {
        __syncthreads();
        // --- B: async DMA, 40 wave-issues of 1 KB split across 6 waves
        {
            const u16* gq = Wqp + (size_t)k * 10240;
            const u16* gv = Wvp + (size_t)k * 10240;
            for (int i = wv; i < 40; i += 6) {
                int mv = (i >= 20);
                int off = (mv ? i - 20 : i) * 512 + lane * 8;
                gl_lds16((mv ? gv : gq) + off, (mv ? (u16*)sBv : (u16*)sBq) + off);
            }
        }
        // --- A: gathered int8 rows (2 threads/row, 3x16B each), decode->bf16
        {
            int r = r0 + ea;
            int src = (r < N_) ? srcOf[(size_t)k * N_ + r] : -1;
            u16* dst = sA + ea * 104 + jb;
            if (src >= 0) {
                const u8* rp = xq8 + (size_t)src * 128;
                float sc = *(const float*)(rp + 96);
                const uint4* sp = (const uint4*)(rp + jb);
#pragma unroll
                for (int i = 0; i < 3; i++) {
                    uint4 v = sp[i];
                    unsigned int w4[4] = {v.x, v.y, v.z, v.w};
                    u16 o[16];
#pragma unroll
                    for (int q = 0; q < 4; q++)
#pragma unroll
                        for (int b = 0; b < 4; b++) {
                            int iv = (int)(signed char)((w4[q] >> (8 * b)) & 0xffu);
                            o[q * 4 + b] = f2bf((float)iv * sc);
                        }
                    *(uint4*)(dst + i * 16) = *(uint4*)(o);
                    *(uint4*)(dst + i * 16 + 8) = *(uint4*)(o + 8);
                }
            } else {
                uint4 z = make_uint4(0, 0, 0, 0);
#pragma unroll
                for (int i = 0; i < 6; i++)
                    *(uint4*)(dst + i * 8) = z;
            }
        }
        __syncthreads();   // drains vmcnt (DMA) + lgkmcnt (ds_write)
        // --- MFMA: 6 K-steps x 3 n-tiles x 2 matrices
#pragma unroll
        for (int ks = 0; ks < 6; ks++) {
            bf16x8 af = *(const bf16x8*)(sA + (wv * 32 + n32) * 104 + ks * 16 + half * 8);
#pragma unroll
            for (int nt = 0; nt < 3; nt++) {
                bf16x8 bq = *(const bf16x8*)(sBq + (nt * 32 + n32) * 104 + ks * 16 + half * 8);
                accq[nt] = __builtin_amdgcn_mfma_f32_32x32x16_bf16(af, bq, accq[nt], 0, 0, 0);
                bf16x8 bv = *(const bf16x8*)(sBv + (nt * 32 + n32) * 104 + ks * 16 + half * 8);
                accv[nt] = __builtin_amdgcn_mfma_f32_32x32x16_bf16(af, bv, accv[nt], 0, 0, 0);
            }
        }
    }
#pragma unroll
    for (int nt = 0; nt < 3; nt++) {
#pragma unroll
        for (int reg = 0; reg < 16; reg++) {
            int row = (reg & 3) + 8 * (reg >> 2) + 4 * half;
            int r = r0 + wv * 32 + row;
            if (r < N_) {
                yQ[(size_t)r * 96 + nt * 32 + n32] = f2bf(accq[nt][reg]);
                yV[(size_t)r * 96 + nt * 32 + n32] = f2bf(accv[nt][reg]);
            }
        }
    }
    __syncthreads();
    float* sred = (float*)sA;
    for (int pass = 0; pass < 2; pass++) {
        f32x16* acc = pass ? accv : accq;
        float* st = pass ? statsV : statsQ;
#pragma unroll
        for (int nt = 0; nt < 3; nt++) {
            float sv = 0.f, qv = 0.f;
#pragma unroll
            for (int reg = 0; reg < 16; reg++) {
                float a = acc[nt][reg];
                sv += a; qv += a * a;
            }
            sv += __shfl_xor(sv, 32, 64);
            qv += __shfl_xor(qv, 32, 64);
            if (half == 0) {
                sred[wv * 192 + nt * 32 + n32] = sv;
                sred[wv * 192 + 96 + nt * 32 + n32] = qv;
            }
        }
        __syncthreads();
        if (t < 192) {
            float tot = 0.f;
#pragma unroll
            for (int w = 0; w < 6; w++) tot += sred[w * 192 + t];
            atomicAdd(&st[t], tot);
        }
        __syncthreads();
    }
}

// Dense projection: g[r][n] = (relu(bn(yQ[r])) @ Wq2all)[n], n = k*4+c, n<108.
__global__ __launch_bounds__(256) void k_proj(
    const u16* __restrict__ xq, const float* __restrict__ stats,
    const float* __restrict__ gg, const float* __restrict__ bb,
    const u16* __restrict__ Bimg, u16* __restrict__ gout) {
    __shared__ u16 sA[128 * 104];
    __shared__ u16 sB[128 * 104];
    __shared__ float sSc[96], sSh[96];
    const int r0 = blockIdx.x * 128;
    const int t = threadIdx.x;
    const int wv = t >> 6, lane = t & 63;
    const int n32 = lane & 31, half = lane >> 5;
    if (t < 96) {
        float mean = stats[t] * (1.f / N_);
        float var = stats[96 + t] * (1.f / N_) - mean * mean;
        float sc = gg[t] * rsqrtf(fmaxf(var, 0.f) + 1e-5f);
        sSc[t] = sc; sSh[t] = bb[t] - mean * sc;
    }
    for (int i = t; i < 1664; i += 256)
        ((uint4*)sB)[i] = ((const uint4*)Bimg)[i];
    __syncthreads();
    {
        int ea = t >> 1, jca = (t & 1) * 6;
        int r = r0 + ea;
        bool ok = (r < N_);
        const u16* xr = xq + (size_t)(ok ? r : 0) * 96;
#pragma unroll
        for (int i = 0; i < 6; i++) {
            int cb = (jca + i) * 8;
            uint4 v = ok ? *(const uint4*)(xr + cb) : make_uint4(0, 0, 0, 0);
            const u16* pv = (const u16*)&v;
            u16 o[8];
#pragma unroll
            for (int e = 0; e < 8; e++) {
                float h = bf2f(pv[e]);
                h = fmaxf(h * sSc[cb + e] + sSh[cb + e], 0.f);
                o[e] = f2bf(h);
            }
            *(uint4*)(sA + ea * 104 + cb) = *(uint4*)o;
        }
    }
    __syncthreads();
    f32x16 acc[4];
#pragma unroll
    for (int i = 0; i < 4; i++)
#pragma unroll
        for (int j = 0; j < 16; j++) acc[i][j] = 0.f;
#pragma unroll
    for (int ks = 0; ks < 6; ks++) {
        bf16x8 af = *(const bf16x8*)(sA + (wv * 32 + n32) * 104 + ks * 16 + half * 8);
#pragma unroll
        for (int nt = 0; nt < 4; nt++) {
            bf16x8 bf = *(const bf16x8*)(sB + (nt * 32 + n32) * 104 + ks * 16 + half * 8);
            acc[nt] = __builtin_amdgcn_mfma_f32_32x32x16_bf16(af, bf, acc[nt], 0, 0, 0);
        }
    }
#pragma unroll
    for (int nt = 0; nt < 4; nt++) {
        int col = nt * 32 + n32;
        if (col < 108) {
#pragma unroll
            for (int reg = 0; reg < 16; reg++) {
                int row = (reg & 3) + 8 * (reg >> 2) + 4 * half;
                int r = r0 + wv * 32 + row;
                if (r < N_) gout[(size_t)r * 108 + col] = f2bf(acc[nt][reg]);
            }
        }
    }
}

// qf[r][c] = sum_k g[srcOf[k][r]][k*4+c]  — MLP-batched (9 k's in flight)
__global__ __launch_bounds__(256) void k_gather4(
    const u16* __restrict__ g, const int* __restrict__ srcOf,
    float* __restrict__ qf) {
    int idx = blockIdx.x * 256 + threadIdx.x;
    if (idx >= N_ * 4) return;
    int r = idx >> 2, c = idx & 3;
    float a = 0.f;
    int sv[9]; u16 gv[9];
#pragma unroll 1
    for (int kb = 0; kb < 27; kb += 9) {
#pragma unroll
        for (int j = 0; j < 9; j++)
            sv[j] = srcOf[(size_t)(kb + j) * N_ + r];
#pragma unroll
        for (int j = 0; j < 9; j++) {
            int sc = (sv[j] >= 0) ? sv[j] : 0;
            gv[j] = g[(size_t)sc * 108 + (kb + j) * 4 + c];
        }
#pragma unroll
        for (int j = 0; j < 9; j++)
            if (sv[j] >= 0) a += bf2f(gv[j]);
    }
    qf[idx] = a;
}

// ---------------------------------------------------------------------------
__global__ __launch_bounds__(192) void k_bnstats96(const float* __restrict__ xin,
                                                   float* __restrict__ stats) {
    __shared__ float sS[192], sQ[192];
    int t = threadIdx.x;
    int ch = t % 96, half = t / 96;
    float s = 0.f, q = 0.f;
    for (int r = blockIdx.x * 2 + half; r < N_; r += gridDim.x * 2) {
        float v = xin[(size_t)r * 96 + ch];
        s += v; q += v * v;
    }
    sS[t] = s; sQ[t] = q;
    __syncthreads();
    if (t < 96) {
        atomicAdd(&stats[ch], sS[t] + sS[t + 96]);
        atomicAdd(&stats[96 + ch], sQ[t] + sQ[t + 96]);
    }
}

__global__ __launch_bounds__(256) void k_bnstats4(const float* __restrict__ xin,
                                                  float* __restrict__ stats) {
    __shared__ float sS[256], sQ[256];
    int t = threadIdx.x;
    int c = t & 3, sub = t >> 2;
    float s = 0.f, q = 0.f;
    for (int r = blockIdx.x * 64 + sub; r < N_; r += gridDim.x * 64) {
        float v = xin[(size_t)r * 4 + c];
        s += v; q += v * v;
    }
    sS[t] = s; sQ[t] = q;
    __syncthreads();
    for (int off = 128; off >= 4; off >>= 1) {
        if (t < off) { sS[t] += sS[t + off]; sQ[t] += sQ[t + off]; }
        __syncthreads();
    }
    if (t < 4) {
        atomicAdd(&stats[t], sS[t]);
        atomicAdd(&stats[96 + t], sQ[t]);
    }
}

// f32 in/out (MODE 0: relu(bn)  MODE 2: relu(bn)+aux)
template <int C, int MODE>
__global__ __launch_bounds__(256) void k_bnapply(float* __restrict__ y,
                                                 const float* __restrict__ stats,
                                                 const float* __restrict__ g,
                                                 const float* __restrict__ b,
                                                 const float* __restrict__ aux) {
    int idx = blockIdx.x * 256 + threadIdx.x;
    if (idx >= N_ * C) return;
    int ch = idx % C;
    float mean = stats[ch] * (1.f / N_);
    float var = stats[96 + ch] * (1.f / N_) - mean * mean;
    float scale = g[ch] * rsqrtf(fmaxf(var, 0.f) + 1e-5f);
    float v = (y[idx] - mean) * scale + b[ch];
    v = fmaxf(v, 0.f);
    if (MODE == 2) v += aux[idx];
    y[idx] = v;
}

// v-branch: V = relu(bn(yV)) + relu(bn(pebRAW)) -> row-scaled UNSIGNED int8
// (128B rows: bytes 0..95 = q (V>=0, scale=max/255), bytes 96..99 = scale).
// 192 threads = 2 rows x 96 channels; LDS tree for per-row max.
__global__ __launch_bounds__(192) void k_bnv8(
    const u16* __restrict__ yin, const float* __restrict__ stats,
    const float* __restrict__ g, const float* __restrict__ b,
    const float* __restrict__ aux, const float* __restrict__ statsP,
    const float* __restrict__ gp2, const float* __restrict__ bp2,
    u8* __restrict__ vq8) {
    __shared__ float red[2][96];
    __shared__ float ssc[2];
    int t = threadIdx.x;
    int half = t / 96, ch = t - half * 96;
    int r = blockIdx.x * 2 + half;
    // bn of yV
    float mean = stats[ch] * (1.f / N_);
    float var = stats[96 + ch] * (1.f / N_) - mean * mean;
    float sc = g[ch] * rsqrtf(fmaxf(var, 0.f) + 1e-5f);
    float v = (bf2f(yin[(size_t)r * 96 + ch]) - mean) * sc + b[ch];
    v = fmaxf(v, 0.f);
    // + relu(bn(peb)) repeat
    int c = ch / 24;
    float pm = statsP[c] * (1.f / N_);
    float pv = statsP[96 + c] * (1.f / N_) - pm * pm;
    float psc = gp2[c] * rsqrtf(fmaxf(pv, 0.f) + 1e-5f);
    v += fmaxf(aux[(size_t)r * 4 + c] * psc + (bp2[c] - pm * psc), 0.f);
    // per-row max via LDS tree (96 -> 48 -> 24 -> 12 -> 6)
    red[half][ch] = v;
    __syncthreads();
    if (ch < 48) red[half][ch] = fmaxf(red[half][ch], red[half][ch + 48]);
    __syncthreads();
    if (ch < 24) red[half][ch] = fmaxf(red[half][ch], red[half][ch + 24]);
    __syncthreads();
    if (ch < 12) red[half][ch] = fmaxf(red[half][ch], red[half][ch + 12]);
    __syncthreads();
    if (ch < 6)  red[half][ch] = fmaxf(red[half][ch], red[half][ch + 6]);
    __syncthreads();
    if (ch == 0) {
        float m = red[half][0];
#pragma unroll
        for (int i = 1; i < 6; i++) m = fmaxf(m, red[half][i]);
        ssc[half] = m;
    }
    __syncthreads();
    float m = ssc[half];
    float inv = (m > 0.f) ? 255.f / m : 0.f;
    float q = rintf(v * inv);
    vq8[(size_t)r * 128 + ch] = (u8)fminf(q, 255.f);
    if (ch == 0) *(float*)(vq8 + (size_t)r * 128 + 96) =
        (m > 0.f) ? m * (1.f / 255.f) : 0.f;
}

// pe1 fused with its BN stats: h = coords @ Wp1 (bf16 out) + per-ch sum/sumsq
__global__ __launch_bounds__(192) void k_pe1s(const float* __restrict__ coords,
                                              const float* __restrict__ Wp1,
                                              u16* __restrict__ out,
                                              float* __restrict__ stats) {
    __shared__ float sS[192], sQ[192];
    int t = threadIdx.x;
    int ch = t % 96, half = t / 96;
    float w0 = Wp1[ch], w1 = Wp1[96 + ch], w2 = Wp1[192 + ch];
    float s = 0.f, q = 0.f;
    for (int r = blockIdx.x * 2 + half; r < N_; r += gridDim.x * 2) {
        float c0 = coords[r * 3], c1 = coords[r * 3 + 1], c2 = coords[r * 3 + 2];
        float v = c0 * w0 + c1 * w1 + c2 * w2;
        out[(size_t)r * 96 + ch] = f2bf(v);
        s += v; q += v * v;
    }
    sS[t] = s; sQ[t] = q;
    __syncthreads();
    if (t < 96) {
        atomicAdd(&stats[ch], sS[t] + sS[t + 96]);
        atomicAdd(&stats[96 + ch], sQ[t] + sQ[t + 96]);
    }
}

// pe2 with inline bn+relu of h1 (RAW pe2 output; its bn applied in k_bnv8)
__global__ __launch_bounds__(256) void k_pe2b(const u16* __restrict__ hin,
                                              const float* __restrict__ stats,
                                              const float* __restrict__ gp,
                                              const float* __restrict__ bp,
                                              const float* __restrict__ Wp2,
                                              float* __restrict__ out) {
    __shared__ float sSc[96], sSh[96], sW[384];
    int t = threadIdx.x;
    if (t < 96) {
        float mean = stats[t] * (1.f / N_);
        float var = stats[96 + t] * (1.f / N_) - mean * mean;
        float sc = gp[t] * rsqrtf(fmaxf(var, 0.f) + 1e-5f);
        sSc[t] = sc; sSh[t] = bp[t] - mean * sc;
    }
    for (int i = t; i < 384; i += 256) sW[i] = Wp2[i];
    __syncthreads();
    int idx = blockIdx.x * 256 + t;
    if (idx >= N_ * 4) return;
    int r = idx >> 2, c = idx & 3;
    const u16* hr = hin + (size_t)r * 96;
    float acc = 0.f;
#pragma unroll 4
    for (int j = 0; j < 96; j++) {
        float h = fmaxf(bf2f(hr[j]) * sSc[j] + sSh[j], 0.f);
        acc += h * sW[j * 4 + c];
    }
    out[idx] = acc;
}

// ---------------------------------------------------------------------------
// MFMA attention logits (32 rows/block), bf16 LDS softmax state.
// qf is RAW gather4 output; bn+relu (statsQ, gq2, bq2) applied inline.
__global__ __launch_bounds__(256) void k_attn_logits_mfma(
    const float* __restrict__ qf, const int* __restrict__ srcOf,
    const float* __restrict__ rowAbs,
    const u16* __restrict__ w1b, const float* __restrict__ b1,
    const u16* __restrict__ w2b, const float* __restrict__ b2,
    const float* __restrict__ statsQ, const float* __restrict__ gq2,
    const float* __restrict__ bq2,
    u16* __restrict__ wb) {
    __shared__ u16 hbuf[4][16 * 104];
    __shared__ u16 slogb[32][176];
    __shared__ u16 smk16[32][44];
    const int t = threadIdx.x;
    const int wv = t >> 6, lane = t & 63;
    const int col = lane & 15, quad = lane >> 4;
    const int r0 = blockIdx.x * 32;

    float qsc[4], qsh[4];
#pragma unroll
    for (int c = 0; c < 4; c++) {
        float mean = statsQ[c] * (1.f / N_);
        float var = statsQ[96 + c] * (1.f / N_) - mean * mean;
        float s = gq2[c] * rsqrtf(fmaxf(var, 0.f) + 1e-5f);
        qsc[c] = s; qsh[c] = bq2[c] - mean * s;
    }

    bf16x8 w1f[6];
    float b1v[6];
#pragma unroll
    for (int nt = 0; nt < 6; nt++) {
        w1f[nt] = *(const bf16x8*)(w1b + (nt * 16 + col) * 32 + quad * 8);
        b1v[nt] = b1[nt * 16 + col];
    }
    bf16x8 w2f[3];
#pragma unroll
    for (int kk = 0; kk < 3; kk++)
        w2f[kk] = *(const bf16x8*)(w2b + col * 96 + kk * 32 + quad * 8);
    float b2v = b2[col & 3];

    u16* hb = hbuf[wv];
    for (int tt = 0; tt < 22; tt++) {
        int tileBase = (wv * 22 + tt) * 16;
        bf16x8 af = (bf16x8){0, 0, 0, 0, 0, 0, 0, 0};
        if (quad == 0) {
            int P = tileBase + col;
            int rL = P / 44, k = P - rL * 44;
            int kc = (k < 43) ? k : 42;
            int r = r0 + rL;
            int s = srcOf[(size_t)kc * N_ + r];
            if (k == 43) s = -1;
            int sc = (s >= 0) ? s : 0;
            float mk = (s >= 0 && rowAbs[sc] > 0.f) ? 1.f : 0.f;
            float4 qs = *(const float4*)(qf + (size_t)sc * 4);
            float4 qr = *(const float4*)(qf + (size_t)r * 4);
            qs.x = fmaxf(qs.x * qsc[0] + qsh[0], 0.f);
            qs.y = fmaxf(qs.y * qsc[1] + qsh[1], 0.f);
            qs.z = fmaxf(qs.z * qsc[2] + qsh[2], 0.f);
            qs.w = fmaxf(qs.w * qsc[3] + qsh[3], 0.f);
            qr.x = fmaxf(qr.x * qsc[0] + qsh[0], 0.f);
            qr.y = fmaxf(qr.y * qsc[1] + qsh[1], 0.f);
            qr.z = fmaxf(qr.z * qsc[2] + qsh[2], 0.f);
            qr.w = fmaxf(qr.w * qsc[3] + qsh[3], 0.f);
            af[0] = (short)f2bf((qs.x - qr.x) * mk);
            af[1] = (short)f2bf((qs.y - qr.y) * mk);
            af[2] = (short)f2bf((qs.z - qr.z) * mk);
            af[3] = (short)f2bf((qs.w - qr.w) * mk);
            if (k < 43) smk16[rL][k] = (u16)(mk > 0.f ? 1 : 0);
        }
        f32x4 c1[6];
#pragma unroll
        for (int nt = 0; nt < 6; nt++) {
            c1[nt] = (f32x4){0.f, 0.f, 0.f, 0.f};
            c1[nt] = __builtin_amdgcn_mfma_f32_16x16x32_bf16(af, w1f[nt], c1[nt], 0, 0, 0);
        }
#pragma unroll
        for (int nt = 0; nt < 6; nt++) {
#pragma unroll
            for (int rg = 0; rg < 4; rg++) {
                float h = fmaxf(c1[nt][rg] + b1v[nt], 0.f);
                hb[(quad * 4 + rg) * 104 + nt * 16 + col] = f2bf(h);
            }
        }
        f32x4 acc2 = (f32x4){0.f, 0.f, 0.f, 0.f};
#pragma unroll
        for (int kk = 0; kk < 3; kk++) {
            bf16x8 a2 = *(const bf16x8*)(hb + col * 104 + kk * 32 + quad * 8);
            acc2 = __builtin_amdgcn_mfma_f32_16x16x32_bf16(a2, w2f[kk], acc2, 0, 0, 0);
        }
        if (col < 4) {
#pragma unroll
            for (int rg = 0; rg < 4; rg++) {
                int P = tileBase + quad * 4 + rg;
                int rL = P / 44, k = P - rL * 44;
                if (k < 43) {
                    float mval = (float)smk16[rL][k];
                    slogb[rL][k * 4 + col] = f2bf((acc2[rg] + b2v) * mval);
                }
            }
        }
    }
    __syncthreads();

    if (t < 128) {
        int rL = t >> 2, c = t & 3;
        float mx = 0.f;
        for (int k = 0; k < K_; k++) mx = fmaxf(mx, bf2f(slogb[rL][k * 4 + c]));
        float den = 0.f;
        for (int k = 0; k < K_; k++) den += __expf(bf2f(slogb[rL][k * 4 + c]) - mx);
        float inv = 1.f / den;
        for (int k = 0; k < K_; k++)
            slogb[rL][k * 4 + c] = f2bf(__expf(bf2f(slogb[rL][k * 4 + c]) - mx) * inv);
    }
    __syncthreads();

    for (int p = t; p < 32 * 43; p += 256) {
        int rL = p / 43, k = p - rL * 43;
        int idxk = (k < 27) ? k : ((k < 35) ? (k - 27) : (k - 35));
        u16 mk = smk16[rL][k];
        ushort4 wout = make_ushort4(0, 0, 0, 0);
        if (mk) {
            wout.x = slogb[rL][idxk * 4 + 0];
            wout.y = slogb[rL][idxk * 4 + 1];
            wout.z = slogb[rL][idxk * 4 + 2];
            wout.w = slogb[rL][idxk * 4 + 3];
        }
        *(ushort4*)(wb + ((size_t)(r0 + rL) * 44 + k) * 4) = wout;
    }
}

// out[r][ch] = sum_k wb[r][k][cg] * V[src_k[r]][ch]
// MLP-batched 8-deep; V rows = row-scaled u8, 1 cache line (128B stride).
__global__ __launch_bounds__(256) void k_attn_gather(
    const u8* __restrict__ vq8, const u16* __restrict__ wb,
    const int* __restrict__ srcOf, float* __restrict__ out) {
    int idx = blockIdx.x * 256 + threadIdx.x;
    int r = idx / 24, c4 = idx - r * 24;
    if (r >= N_) return;
    int cg = c4 / 6;
    const u16* wrow = wb + (size_t)r * 176 + cg;
    float a0 = 0.f, a1 = 0.f, a2 = 0.f, a3 = 0.f;
    int sv[8]; float wv[8]; unsigned int vv[8]; float scv[8];
#pragma unroll 1
    for (int kb = 0; kb < 40; kb += 8) {
#pragma unroll
        for (int j = 0; j < 8; j++)
            sv[j] = srcOf[(size_t)(kb + j) * N_ + r];
#pragma unroll
        for (int j = 0; j < 8; j++)
            wv[j] = bf2f(wrow[(size_t)(kb + j) * 4]);
#pragma unroll
        for (int j = 0; j < 8; j++) {
            int sc = (sv[j] >= 0) ? sv[j] : 0;
            const u8* rp = vq8 + (size_t)sc * 128;
            vv[j] = *(const unsigned int*)(rp + c4 * 4);
            scv[j] = *(const float*)(rp + 96);
        }
#pragma unroll
        for (int j = 0; j < 8; j++) {
            float w = (sv[j] >= 0) ? wv[j] * scv[j] : 0.f;
            a0 += w * (float)(vv[j] & 0xffu);
            a1 += w * (float)((vv[j] >> 8) & 0xffu);
            a2 += w * (float)((vv[j] >> 16) & 0xffu);
            a3 += w * (float)((vv[j] >> 24) & 0xffu);
        }
    }
#pragma unroll
    for (int j = 0; j < 3; j++)
        sv[j] = srcOf[(size_t)(40 + j) * N_ + r];
#pragma unroll
    for (int j = 0; j < 3; j++)
        wv[j] = bf2f(wrow[(size_t)(40 + j) * 4]);
#pragma unroll
    for (int j = 0; j < 3; j++) {
        int sc = (sv[j] >= 0) ? sv[j] : 0;
        const u8* rp = vq8 + (size_t)sc * 128;
        vv[j] = *(const unsigned int*)(rp + c4 * 4);
        scv[j] = *(const float*)(rp + 96);
    }
#pragma unroll
    for (int j = 0; j < 3; j++) {
        float w = (sv[j] >= 0) ? wv[j] * scv[j] : 0.f;
        a0 += w * (float)(vv[j] & 0xffu);
        a1 += w * (float)((vv[j] >> 8) & 0xffu);
        a2 += w * (float)((vv[j] >> 16) & 0xffu);
        a3 += w * (float)((vv[j] >> 24) & 0xffu);
    }
    *(float4*)(out + (size_t)r * 96 + c4 * 4) = make_float4(a0, a1, a2, a3);
}

// ---------------------------------------------------------------------------
extern "C" void kernel_launch(void* const* d_in, const int* in_sizes, int n_in,
                              void* d_out, int out_size, void* d_ws, size_t ws_size,
                              hipStream_t stream) {
    const float* x      = (const float*)d_in[0];
    const float* coords = (const float*)d_in[1];
    const float* Wq1 = (const float*)d_in[2];
    const float* gq1 = (const float*)d_in[3];
    const float* bq1 = (const float*)d_in[4];
    const float* Wq2 = (const float*)d_in[5];
    const float* gq2 = (const float*)d_in[6];
    const float* bq2 = (const float*)d_in[7];
    const float* Wv  = (const float*)d_in[8];
    const float* gv  = (const float*)d_in[9];
    const float* bv  = (const float*)d_in[10];
    const float* Wp1 = (const float*)d_in[11];
    const float* gp1 = (const float*)d_in[12];
    const float* bp1 = (const float*)d_in[13];
    const float* Wp2 = (const float*)d_in[14];
    const float* gp2 = (const float*)d_in[15];
    const float* bp2 = (const float*)d_in[16];
    const float* W1  = (const float*)d_in[17];
    const float* b1  = (const float*)d_in[18];
    const float* W2  = (const float*)d_in[19];
    const float* b2  = (const float*)d_in[20];
    const float* g_out = (const float*)d_in[21];
    const float* b_out = (const float*)d_in[22];
    const int* kmaps = (const int*)d_in[23];
    float* out = (float*)d_out;

    // ---- workspace map (peak < 95 MB) ----
    char* ws = (char*)d_ws;
    int*   srcOf  = (int*)ws;                     //  0 .. 17.2M        all
    float* rowAbs = (float*)(ws + 17200000);      // 17.2 .. 17.6M      -> logits
    float* stats  = (float*)(ws + 17600000);      // +4,608             all
    u16*   w1b    = (u16*)(ws + 17604608);        // +6,144             -> logits
    u16*   w2b    = (u16*)(ws + 17610752);        // +3,072             -> logits
    u16*   Bimg   = (u16*)(ws + 17613824);        // +26,624            -> proj
    u16*   Wq1p   = (u16*)(ws + 17640448);        // +552,960           -> conv96
    u16*   Wvp    = (u16*)(ws + 18193408);        // +552,960           -> conv96
    u8*    xq8    = (u8*)(ws + 18746368);         // +12.8M  -> conv96
    u16*   bufQb  = (u16*)(ws + 31546368);        // +19.2M  conv96 -> proj
    u16*   bufVb  = (u16*)(ws + 50746368);        // +19.2M  conv96 -> bnv8
    u16*   gbuf   = (u16*)(ws + 69946368);        // +21.6M  proj -> gather4
    float* qf     = (float*)(ws + 91546368);      // +1.6M   gather4 -> logits
    float* peb    = (float*)(ws + 93146368);      // +1.6M   pe2b -> bnv8
    u16*   pescr  = (u16*)(ws + 18746368);        // 19.2M overlay (xq8+bufQb head; dead)
    u8*    vq8    = (u8*)(ws + 69946368);         // 12.8M overlay gbuf (dead after gather4)
    u16*   wbuf   = (u16*)(ws + 18746368);        // 35.2M overlay (pescr/bufQb/bufVb dead)

    hipMemsetAsync(srcOf, 0xFF, (size_t)K_ * N_ * 4, stream);  // -1
    hipMemsetAsync(stats, 0, 6 * 192 * 4, stream);

    k_build_srcof<<<(K_ * M_ + 255) / 256, 256, 0, stream>>>(kmaps, srcOf);
    k_rowabs_cvti8<<<N_ / 4, 256, 0, stream>>>(x, rowAbs, xq8);
    k_wt96p<<<(KC_ * 9216 + 255) / 256, 256, 0, stream>>>(Wq1, Wq1p);
    k_wt96p<<<(KC_ * 9216 + 255) / 256, 256, 0, stream>>>(Wv, Wvp);
    k_wtB<<<52, 256, 0, stream>>>(Wq2, Bimg);
    k_w12b<<<12, 256, 0, stream>>>(W1, W2, w1b, w2b);

    const int cbD  = (N_ + 191) / 192;   // 521
    const int eb96 = N_ * 96 / 256;      // 37500
    const int eb24 = (N_ * 24) / 256;    // 9375
    const int eb4  = (N_ * 4 + 255) / 256;

    // P2: both convs (int8 A-gather, 1 line/row) + their BN stats in one pass
    k_conv96_dual<<<cbD, 384, 0, stream>>>(xq8, Wq1p, Wvp, srcOf, bufQb, bufVb,
                                           stats + 0 * 192, stats + 4 * 192);

    // P3/P4: q-branch: dense projection (bn inline) -> 8B gather -> stats
    // (qf stays RAW; bn+relu applied inline in attn_logits)
    k_proj<<<(N_ + 127) / 128, 256, 0, stream>>>(bufQb, stats + 0 * 192, gq1, bq1,
                                                 Bimg, gbuf);
    k_gather4<<<eb4, 256, 0, stream>>>(gbuf, srcOf, qf);
    k_bnstats4<<<512, 256, 0, stream>>>(qf, stats + 1 * 192);

    // P5: pe chain (pe1+stats fused; pe2 with inline bn of h1; peb stays RAW)
    k_pe1s<<<512, 192, 0, stream>>>(coords, Wp1, pescr, stats + 2 * 192);
    k_pe2b<<<eb4, 256, 0, stream>>>(pescr, stats + 2 * 192, gp1, bp1, Wp2, peb);
    k_bnstats4<<<512, 256, 0, stream>>>(peb, stats + 3 * 192);

    // P6: v-branch: bn+relu + relu(bn(peb)) -> row-scaled u8 vq8 (1-line rows)
    k_bnv8<<<N_ / 2, 192, 0, stream>>>(bufVb, stats + 4 * 192, gv, bv, peb,
                                       stats + 3 * 192, gp2, bp2, vq8);

    // P7/P8: attention (separate kernels; gather at full occupancy)
    k_attn_logits_mfma<<<N_ / 32, 256, 0, stream>>>(qf, srcOf, rowAbs, w1b, b1,
                                                    w2b, b2, stats + 1 * 192,
                                                    gq2, bq2, wbuf);
    k_attn_gather<<<eb24, 256, 0, stream>>>(vq8, wbuf, srcOf, out);

    // P9: out = relu(bn(out)) + x
    k_bnstats96<<<512, 192, 0, stream>>>(out, stats + 5 * 192);
    k_bnapply<96, 2><<<eb96, 256, 0, stream>>>(out, stats + 5 * 192, g_out, b_out, x);
}

// Round 10
// 876.468 us; speedup vs baseline: 1.0488x; 1.0410x over previous
//
#include <hip/hip_runtime.h>
#include <math.h>

#define N_  100000
#define P_  96
#define V_  4
#define M_  70000
#define K_  43
#define KC_ 27

typedef unsigned short u16;
typedef unsigned char u8;
typedef __attribute__((ext_vector_type(8))) short bf16x8;
typedef __attribute__((ext_vector_type(4))) float f32x4;
typedef __attribute__((ext_vector_type(16))) float f32x16;

__device__ __forceinline__ u16 f2bf(float f) {
    unsigned int u = __float_as_uint(f);
    u += 0x7fffu + ((u >> 16) & 1u);   // round-to-nearest-even
    return (u16)(u >> 16);
}
__device__ __forceinline__ float bf2f(u16 h) {
    return __uint_as_float(((unsigned int)h) << 16);
}

// async global->LDS DMA, 16 B per lane; dest = wave-uniform base + lane*16
__device__ __forceinline__ void gl_lds16(const u16* g, u16* l) {
    __builtin_amdgcn_global_load_lds(
        (const __attribute__((address_space(1))) void*)g,
        (__attribute__((address_space(3))) void*)l, 16, 0, 0);
}

// ---------------------------------------------------------------------------
__global__ __launch_bounds__(256) void k_build_srcof(const int* __restrict__ km,
                                                     int* __restrict__ srcOf) {
    int idx = blockIdx.x * 256 + threadIdx.x;
    if (idx >= K_ * M_) return;
    int k = idx / M_;
    int e = idx - k * M_;
    const int* p = km + (size_t)(k * M_ + e) * 2;
    srcOf[(size_t)k * N_ + p[1]] = p[0];
}

// rowAbs[r] = sum_j |x[r][j]|  AND  xb = bf16(x), stride 96 (proven R0 layout)
__global__ __launch_bounds__(256) void k_rowabs_cvt(const float* __restrict__ x,
                                                    float* __restrict__ rowAbs,
                                                    u16* __restrict__ xb) {
    int row = blockIdx.x * 4 + (threadIdx.x >> 6);
    int lane = threadIdx.x & 63;
    if (row >= N_) return;
    const float* xr = x + (size_t)row * 96;
    float s = 0.f;
    for (int j = lane; j < 96; j += 64) {
        float v = xr[j];
        s += fabsf(v);
        xb[(size_t)row * 96 + j] = f2bf(v);
    }
#pragma unroll
    for (int o = 32; o > 0; o >>= 1) s += __shfl_down(s, o, 64);
    if (lane == 0) rowAbs[row] = s;
}

// Padded weight image for async staging: Wp[k*10240 + n*104 + j] = bf16(W[k][j][n])
__global__ __launch_bounds__(256) void k_wt96p(const float* __restrict__ W,
                                               u16* __restrict__ Wp) {
    int idx = blockIdx.x * 256 + threadIdx.x;
    if (idx >= KC_ * 96 * 96) return;
    int k = idx / 9216, rem = idx - k * 9216, n = rem / 96, j = rem - n * 96;
    Wp[(size_t)k * 10240 + n * 104 + j] = f2bf(W[(size_t)k * 9216 + j * 96 + n]);
}

// Bimg[n*104 + j] = bf16(Wq2[n/4][j][n&3]) for n<108,j<96 else 0  (128x104 image)
__global__ __launch_bounds__(256) void k_wtB(const float* __restrict__ W,
                                             u16* __restrict__ Bimg) {
    int idx = blockIdx.x * 256 + threadIdx.x;
    if (idx >= 128 * 104) return;
    int n = idx / 104, j = idx - n * 104;
    u16 v = 0;
    if (j < 96 && n < 108) {
        int ks = n >> 2, c = n & 3;
        v = f2bf(W[(size_t)ks * 384 + j * 4 + c]);
    }
    Bimg[idx] = v;
}

// w1b[j][c32] = bf16(W1[c][j]) c<4 else 0; w2b[n16][j] = bf16(W2[j][n]) n<4 else 0
__global__ __launch_bounds__(256) void k_w12b(const float* __restrict__ W1,
                                              const float* __restrict__ W2,
                                              u16* __restrict__ w1b,
                                              u16* __restrict__ w2b) {
    int t = blockIdx.x * 256 + threadIdx.x;
    if (t < 96 * 32) {
        int j = t >> 5, c = t & 31;
        w1b[t] = (c < 4) ? f2bf(W1[c * 96 + j]) : (u16)0;
    }
    if (t < 16 * 96) {
        int n = t / 96, j = t - n * 96;
        w2b[t] = (n < 4) ? f2bf(W2[j * 4 + n]) : (u16)0;
    }
}

// ---------------------------------------------------------------------------
// Dual conv, 32x32x16 MFMA, 192 rows/block, 384 threads (6 waves) — proven
// R0 structure. bf16 A-gather (2 lines/row, 2-thr/row x 6x16B) keeps 64
// lines in flight per wave — the random-line rate scales with that queue
// depth (R9 lesson: 1-line rows halve the rate, no win).
__global__ __launch_bounds__(384, 3) void k_conv96_dual(
    const u16* __restrict__ xb, const u16* __restrict__ Wqp,
    const u16* __restrict__ Wvp, const int* __restrict__ srcOf,
    u16* __restrict__ yQ, u16* __restrict__ yV,
    float* __restrict__ statsQ, float* __restrict__ statsV) {
    __shared__ u16 sA[192 * 104];   // 39,936 B
    __shared__ u16 sBq[10240];      // 20,480 B (96x104 padded image)
    __shared__ u16 sBv[10240];      // 20,480 B
    const int r0 = blockIdx.x * 192;
    const int t = threadIdx.x;
    const int wv = t / 64, lane = t & 63;
    const int n32 = lane & 31, half = lane >> 5;
    const int ea = t >> 1, jca = (t & 1) * 6;
    f32x16 accq[3], accv[3];
#pragma unroll
    for (int i = 0; i < 3; i++) {
#pragma unroll
        for (int j = 0; j < 16; j++) { accq[i][j] = 0.f; accv[i][j] = 0.f; }
    }

    for (int k = 0; k < KC_; k++) {
        __syncthreads();
        // --- B: async DMA, 40 wave-issues of 1 KB split across 6 waves
        {
            const u16* gq = Wqp + (size_t)k * 10240;
            const u16* gv = Wvp + (size_t)k * 10240;
            for (int i = wv; i < 40; i += 6) {
                int mv = (i >= 20);
                int off = (mv ? i - 20 : i) * 512 + lane * 8;
                gl_lds16((mv ? gv : gq) + off, (mv ? (u16*)sBv : (u16*)sBq) + off);
            }
        }
        // --- A: gathered rows (2 threads per row, 6 x 16B each)
        {
            int r = r0 + ea;
            int src = (r < N_) ? srcOf[(size_t)k * N_ + r] : -1;
            if (src >= 0) {
                const uint4* sp = (const uint4*)(xb + (size_t)src * 96);
#pragma unroll
                for (int i = 0; i < 6; i++)
                    *(uint4*)(sA + ea * 104 + (jca + i) * 8) = sp[jca + i];
            } else {
                uint4 z = make_uint4(0, 0, 0, 0);
#pragma unroll
                for (int i = 0; i < 6; i++)
                    *(uint4*)(sA + ea * 104 + (jca + i) * 8) = z;
            }
        }
        __syncthreads();   // drains vmcnt (DMA) + lgkmcnt (ds_write)
        // --- MFMA: 6 K-steps x 3 n-tiles x 2 matrices
#pragma unroll
        for (int ks = 0; ks < 6; ks++) {
            bf16x8 af = *(const bf16x8*)(sA + (wv * 32 + n32) * 104 + ks * 16 + half * 8);
#pragma unroll
            for (int nt = 0; nt < 3; nt++) {
                bf16x8 bq = *(const bf16x8*)(sBq + (nt * 32 + n32) * 104 + ks * 16 + half * 8);
                accq[nt] = __builtin_amdgcn_mfma_f32_32x32x16_bf16(af, bq, accq[nt], 0, 0, 0);
                bf16x8 bv = *(const bf16x8*)(sBv + (nt * 32 + n32) * 104 + ks * 16 + half * 8);
                accv[nt] = __builtin_amdgcn_mfma_f32_32x32x16_bf16(af, bv, accv[nt], 0, 0, 0);
            }
        }
    }
    // --- outputs (bf16); C/D: col=lane&31, row=(reg&3)+8*(reg>>2)+4*half
#pragma unroll
    for (int nt = 0; nt < 3; nt++) {
#pragma unroll
        for (int reg = 0; reg < 16; reg++) {
            int row = (reg & 3) + 8 * (reg >> 2) + 4 * half;
            int r = r0 + wv * 32 + row;
            if (r < N_) {
                yQ[(size_t)r * 96 + nt * 32 + n32] = f2bf(accq[nt][reg]);
                yV[(size_t)r * 96 + nt * 32 + n32] = f2bf(accv[nt][reg]);
            }
        }
    }
    // --- fused BN stats (invalid rows contribute exact zeros)
    __syncthreads();
    float* sred = (float*)sA;   // 6 waves x 192 floats
    for (int pass = 0; pass < 2; pass++) {
        f32x16* acc = pass ? accv : accq;
        float* st = pass ? statsV : statsQ;
#pragma unroll
        for (int nt = 0; nt < 3; nt++) {
            float sv = 0.f, qv = 0.f;
#pragma unroll
            for (int reg = 0; reg < 16; reg++) {
                float a = acc[nt][reg];
                sv += a; qv += a * a;
            }
            sv += __shfl_xor(sv, 32, 64);
            qv += __shfl_xor(qv, 32, 64);
            if (half == 0) {
                sred[wv * 192 + nt * 32 + n32] = sv;
                sred[wv * 192 + 96 + nt * 32 + n32] = qv;
            }
        }
        __syncthreads();
        if (t < 192) {
            float tot = 0.f;
#pragma unroll
            for (int w = 0; w < 6; w++) tot += sred[w * 192 + t];
            atomicAdd(&st[t], tot);
        }
        __syncthreads();
    }
}

// Dense projection: g[r][n] = (relu(bn(yQ[r])) @ Wq2all)[n], n = k*4+c, n<108.
__global__ __launch_bounds__(256) void k_proj(
    const u16* __restrict__ xq, const float* __restrict__ stats,
    const float* __restrict__ gg, const float* __restrict__ bb,
    const u16* __restrict__ Bimg, u16* __restrict__ gout) {
    __shared__ u16 sA[128 * 104];
    __shared__ u16 sB[128 * 104];
    __shared__ float sSc[96], sSh[96];
    const int r0 = blockIdx.x * 128;
    const int t = threadIdx.x;
    const int wv = t >> 6, lane = t & 63;
    const int n32 = lane & 31, half = lane >> 5;
    if (t < 96) {
        float mean = stats[t] * (1.f / N_);
        float var = stats[96 + t] * (1.f / N_) - mean * mean;
        float sc = gg[t] * rsqrtf(fmaxf(var, 0.f) + 1e-5f);
        sSc[t] = sc; sSh[t] = bb[t] - mean * sc;
    }
    for (int i = t; i < 1664; i += 256)
        ((uint4*)sB)[i] = ((const uint4*)Bimg)[i];
    __syncthreads();
    {
        int ea = t >> 1, jca = (t & 1) * 6;
        int r = r0 + ea;
        bool ok = (r < N_);
        const u16* xr = xq + (size_t)(ok ? r : 0) * 96;
#pragma unroll
        for (int i = 0; i < 6; i++) {
            int cb = (jca + i) * 8;
            uint4 v = ok ? *(const uint4*)(xr + cb) : make_uint4(0, 0, 0, 0);
            const u16* pv = (const u16*)&v;
            u16 o[8];
#pragma unroll
            for (int e = 0; e < 8; e++) {
                float h = bf2f(pv[e]);
                h = fmaxf(h * sSc[cb + e] + sSh[cb + e], 0.f);
                o[e] = f2bf(h);
            }
            *(uint4*)(sA + ea * 104 + cb) = *(uint4*)o;
        }
    }
    __syncthreads();
    f32x16 acc[4];
#pragma unroll
    for (int i = 0; i < 4; i++)
#pragma unroll
        for (int j = 0; j < 16; j++) acc[i][j] = 0.f;
#pragma unroll
    for (int ks = 0; ks < 6; ks++) {
        bf16x8 af = *(const bf16x8*)(sA + (wv * 32 + n32) * 104 + ks * 16 + half * 8);
#pragma unroll
        for (int nt = 0; nt < 4; nt++) {
            bf16x8 bf = *(const bf16x8*)(sB + (nt * 32 + n32) * 104 + ks * 16 + half * 8);
            acc[nt] = __builtin_amdgcn_mfma_f32_32x32x16_bf16(af, bf, acc[nt], 0, 0, 0);
        }
    }
#pragma unroll
    for (int nt = 0; nt < 4; nt++) {
        int col = nt * 32 + n32;
        if (col < 108) {
#pragma unroll
            for (int reg = 0; reg < 16; reg++) {
                int row = (reg & 3) + 8 * (reg >> 2) + 4 * half;
                int r = r0 + wv * 32 + row;
                if (r < N_) gout[(size_t)r * 108 + col] = f2bf(acc[nt][reg]);
            }
        }
    }
}

// qf[r][c] = sum_k g[srcOf[k][r]][k*4+c]  — MLP-batched (9 k's in flight)
__global__ __launch_bounds__(256) void k_gather4(
    const u16* __restrict__ g, const int* __restrict__ srcOf,
    float* __restrict__ qf) {
    int idx = blockIdx.x * 256 + threadIdx.x;
    if (idx >= N_ * 4) return;
    int r = idx >> 2, c = idx & 3;
    float a = 0.f;
    int sv[9]; u16 gv[9];
#pragma unroll 1
    for (int kb = 0; kb < 27; kb += 9) {
#pragma unroll
        for (int j = 0; j < 9; j++)
            sv[j] = srcOf[(size_t)(kb + j) * N_ + r];
#pragma unroll
        for (int j = 0; j < 9; j++) {
            int sc = (sv[j] >= 0) ? sv[j] : 0;
            gv[j] = g[(size_t)sc * 108 + (kb + j) * 4 + c];
        }
#pragma unroll
        for (int j = 0; j < 9; j++)
            if (sv[j] >= 0) a += bf2f(gv[j]);
    }
    qf[idx] = a;
}

// ---------------------------------------------------------------------------
__global__ __launch_bounds__(192) void k_bnstats96(const float* __restrict__ xin,
                                                   float* __restrict__ stats) {
    __shared__ float sS[192], sQ[192];
    int t = threadIdx.x;
    int ch = t % 96, half = t / 96;
    float s = 0.f, q = 0.f;
    for (int r = blockIdx.x * 2 + half; r < N_; r += gridDim.x * 2) {
        float v = xin[(size_t)r * 96 + ch];
        s += v; q += v * v;
    }
    sS[t] = s; sQ[t] = q;
    __syncthreads();
    if (t < 96) {
        atomicAdd(&stats[ch], sS[t] + sS[t + 96]);
        atomicAdd(&stats[96 + ch], sQ[t] + sQ[t + 96]);
    }
}

__global__ __launch_bounds__(256) void k_bnstats4(const float* __restrict__ xin,
                                                  float* __restrict__ stats) {
    __shared__ float sS[256], sQ[256];
    int t = threadIdx.x;
    int c = t & 3, sub = t >> 2;
    float s = 0.f, q = 0.f;
    for (int r = blockIdx.x * 64 + sub; r < N_; r += gridDim.x * 64) {
        float v = xin[(size_t)r * 4 + c];
        s += v; q += v * v;
    }
    sS[t] = s; sQ[t] = q;
    __syncthreads();
    for (int off = 128; off >= 4; off >>= 1) {
        if (t < off) { sS[t] += sS[t + off]; sQ[t] += sQ[t + off]; }
        __syncthreads();
    }
    if (t < 4) {
        atomicAdd(&stats[t], sS[t]);
        atomicAdd(&stats[96 + t], sQ[t]);
    }
}

// f32 in/out (MODE 0: relu(bn)  MODE 2: relu(bn)+aux)
template <int C, int MODE>
__global__ __launch_bounds__(256) void k_bnapply(float* __restrict__ y,
                                                 const float* __restrict__ stats,
                                                 const float* __restrict__ g,
                                                 const float* __restrict__ b,
                                                 const float* __restrict__ aux) {
    int idx = blockIdx.x * 256 + threadIdx.x;
    if (idx >= N_ * C) return;
    int ch = idx % C;
    float mean = stats[ch] * (1.f / N_);
    float var = stats[96 + ch] * (1.f / N_) - mean * mean;
    float scale = g[ch] * rsqrtf(fmaxf(var, 0.f) + 1e-5f);
    float v = (y[idx] - mean) * scale + b[ch];
    v = fmaxf(v, 0.f);
    if (MODE == 2) v += aux[idx];
    y[idx] = v;
}

// v-branch: V = relu(bn(yV)) + relu(bn(pebRAW)) -> row-scaled UNSIGNED int8
// (128B rows: bytes 0..95 = q (V>=0, scale=max/255), bytes 96..99 = scale).
// 192 threads = 2 rows x 96 channels; LDS tree for per-row max.
__global__ __launch_bounds__(192) void k_bnv8(
    const u16* __restrict__ yin, const float* __restrict__ stats,
    const float* __restrict__ g, const float* __restrict__ b,
    const float* __restrict__ aux, const float* __restrict__ statsP,
    const float* __restrict__ gp2, const float* __restrict__ bp2,
    u8* __restrict__ vq8) {
    __shared__ float red[2][96];
    __shared__ float ssc[2];
    int t = threadIdx.x;
    int half = t / 96, ch = t - half * 96;
    int r = blockIdx.x * 2 + half;
    float mean = stats[ch] * (1.f / N_);
    float var = stats[96 + ch] * (1.f / N_) - mean * mean;
    float sc = g[ch] * rsqrtf(fmaxf(var, 0.f) + 1e-5f);
    float v = (bf2f(yin[(size_t)r * 96 + ch]) - mean) * sc + b[ch];
    v = fmaxf(v, 0.f);
    int c = ch / 24;
    float pm = statsP[c] * (1.f / N_);
    float pv = statsP[96 + c] * (1.f / N_) - pm * pm;
    float psc = gp2[c] * rsqrtf(fmaxf(pv, 0.f) + 1e-5f);
    v += fmaxf(aux[(size_t)r * 4 + c] * psc + (bp2[c] - pm * psc), 0.f);
    red[half][ch] = v;
    __syncthreads();
    if (ch < 48) red[half][ch] = fmaxf(red[half][ch], red[half][ch + 48]);
    __syncthreads();
    if (ch < 24) red[half][ch] = fmaxf(red[half][ch], red[half][ch + 24]);
    __syncthreads();
    if (ch < 12) red[half][ch] = fmaxf(red[half][ch], red[half][ch + 12]);
    __syncthreads();
    if (ch < 6)  red[half][ch] = fmaxf(red[half][ch], red[half][ch + 6]);
    __syncthreads();
    if (ch == 0) {
        float m = red[half][0];
#pragma unroll
        for (int i = 1; i < 6; i++) m = fmaxf(m, red[half][i]);
        ssc[half] = m;
    }
    __syncthreads();
    float m = ssc[half];
    float inv = (m > 0.f) ? 255.f / m : 0.f;
    float q = rintf(v * inv);
    vq8[(size_t)r * 128 + ch] = (u8)fminf(q, 255.f);
    if (ch == 0) *(float*)(vq8 + (size_t)r * 128 + 96) =
        (m > 0.f) ? m * (1.f / 255.f) : 0.f;
}

// pe1 fused with its BN stats: h = coords @ Wp1 (bf16 out) + per-ch sum/sumsq
__global__ __launch_bounds__(192) void k_pe1s(const float* __restrict__ coords,
                                              const float* __restrict__ Wp1,
                                              u16* __restrict__ out,
                                              float* __restrict__ stats) {
    __shared__ float sS[192], sQ[192];
    int t = threadIdx.x;
    int ch = t % 96, half = t / 96;
    float w0 = Wp1[ch], w1 = Wp1[96 + ch], w2 = Wp1[192 + ch];
    float s = 0.f, q = 0.f;
    for (int r = blockIdx.x * 2 + half; r < N_; r += gridDim.x * 2) {
        float c0 = coords[r * 3], c1 = coords[r * 3 + 1], c2 = coords[r * 3 + 2];
        float v = c0 * w0 + c1 * w1 + c2 * w2;
        out[(size_t)r * 96 + ch] = f2bf(v);
        s += v; q += v * v;
    }
    sS[t] = s; sQ[t] = q;
    __syncthreads();
    if (t < 96) {
        atomicAdd(&stats[ch], sS[t] + sS[t + 96]);
        atomicAdd(&stats[96 + ch], sQ[t] + sQ[t + 96]);
    }
}

// pe2 with inline bn+relu of h1 (RAW pe2 output; its bn applied in k_bnv8)
__global__ __launch_bounds__(256) void k_pe2b(const u16* __restrict__ hin,
                                              const float* __restrict__ stats,
                                              const float* __restrict__ gp,
                                              const float* __restrict__ bp,
                                              const float* __restrict__ Wp2,
                                              float* __restrict__ out) {
    __shared__ float sSc[96], sSh[96], sW[384];
    int t = threadIdx.x;
    if (t < 96) {
        float mean = stats[t] * (1.f / N_);
        float var = stats[96 + t] * (1.f / N_) - mean * mean;
        float sc = gp[t] * rsqrtf(fmaxf(var, 0.f) + 1e-5f);
        sSc[t] = sc; sSh[t] = bp[t] - mean * sc;
    }
    for (int i = t; i < 384; i += 256) sW[i] = Wp2[i];
    __syncthreads();
    int idx = blockIdx.x * 256 + t;
    if (idx >= N_ * 4) return;
    int r = idx >> 2, c = idx & 3;
    const u16* hr = hin + (size_t)r * 96;
    float acc = 0.f;
#pragma unroll 4
    for (int j = 0; j < 96; j++) {
        float h = fmaxf(bf2f(hr[j]) * sSc[j] + sSh[j], 0.f);
        acc += h * sW[j * 4 + c];
    }
    out[idx] = acc;
}

// ---------------------------------------------------------------------------
// MFMA attention logits (32 rows/block), bf16 LDS softmax state.
// qf is RAW gather4 output; bn+relu (statsQ, gq2, bq2) applied inline.
__global__ __launch_bounds__(256) void k_attn_logits_mfma(
    const float* __restrict__ qf, const int* __restrict__ srcOf,
    const float* __restrict__ rowAbs,
    const u16* __restrict__ w1b, const float* __restrict__ b1,
    const u16* __restrict__ w2b, const float* __restrict__ b2,
    const float* __restrict__ statsQ, const float* __restrict__ gq2,
    const float* __restrict__ bq2,
    u16* __restrict__ wb) {
    __shared__ u16 hbuf[4][16 * 104];
    __shared__ u16 slogb[32][176];
    __shared__ u16 smk16[32][44];
    const int t = threadIdx.x;
    const int wv = t >> 6, lane = t & 63;
    const int col = lane & 15, quad = lane >> 4;
    const int r0 = blockIdx.x * 32;

    float qsc[4], qsh[4];
#pragma unroll
    for (int c = 0; c < 4; c++) {
        float mean = statsQ[c] * (1.f / N_);
        float var = statsQ[96 + c] * (1.f / N_) - mean * mean;
        float s = gq2[c] * rsqrtf(fmaxf(var, 0.f) + 1e-5f);
        qsc[c] = s; qsh[c] = bq2[c] - mean * s;
    }

    bf16x8 w1f[6];
    float b1v[6];
#pragma unroll
    for (int nt = 0; nt < 6; nt++) {
        w1f[nt] = *(const bf16x8*)(w1b + (nt * 16 + col) * 32 + quad * 8);
        b1v[nt] = b1[nt * 16 + col];
    }
    bf16x8 w2f[3];
#pragma unroll
    for (int kk = 0; kk < 3; kk++)
        w2f[kk] = *(const bf16x8*)(w2b + col * 96 + kk * 32 + quad * 8);
    float b2v = b2[col & 3];

    u16* hb = hbuf[wv];
    for (int tt = 0; tt < 22; tt++) {
        int tileBase = (wv * 22 + tt) * 16;
        bf16x8 af = (bf16x8){0, 0, 0, 0, 0, 0, 0, 0};
        if (quad == 0) {
            int P = tileBase + col;
            int rL = P / 44, k = P - rL * 44;
            int kc = (k < 43) ? k : 42;
            int r = r0 + rL;
            int s = srcOf[(size_t)kc * N_ + r];
            if (k == 43) s = -1;
            int sc = (s >= 0) ? s : 0;
            float mk = (s >= 0 && rowAbs[sc] > 0.f) ? 1.f : 0.f;
            float4 qs = *(const float4*)(qf + (size_t)sc * 4);
            float4 qr = *(const float4*)(qf + (size_t)r * 4);
            qs.x = fmaxf(qs.x * qsc[0] + qsh[0], 0.f);
            qs.y = fmaxf(qs.y * qsc[1] + qsh[1], 0.f);
            qs.z = fmaxf(qs.z * qsc[2] + qsh[2], 0.f);
            qs.w = fmaxf(qs.w * qsc[3] + qsh[3], 0.f);
            qr.x = fmaxf(qr.x * qsc[0] + qsh[0], 0.f);
            qr.y = fmaxf(qr.y * qsc[1] + qsh[1], 0.f);
            qr.z = fmaxf(qr.z * qsc[2] + qsh[2], 0.f);
            qr.w = fmaxf(qr.w * qsc[3] + qsh[3], 0.f);
            af[0] = (short)f2bf((qs.x - qr.x) * mk);
            af[1] = (short)f2bf((qs.y - qr.y) * mk);
            af[2] = (short)f2bf((qs.z - qr.z) * mk);
            af[3] = (short)f2bf((qs.w - qr.w) * mk);
            if (k < 43) smk16[rL][k] = (u16)(mk > 0.f ? 1 : 0);
        }
        f32x4 c1[6];
#pragma unroll
        for (int nt = 0; nt < 6; nt++) {
            c1[nt] = (f32x4){0.f, 0.f, 0.f, 0.f};
            c1[nt] = __builtin_amdgcn_mfma_f32_16x16x32_bf16(af, w1f[nt], c1[nt], 0, 0, 0);
        }
#pragma unroll
        for (int nt = 0; nt < 6; nt++) {
#pragma unroll
            for (int rg = 0; rg < 4; rg++) {
                float h = fmaxf(c1[nt][rg] + b1v[nt], 0.f);
                hb[(quad * 4 + rg) * 104 + nt * 16 + col] = f2bf(h);
            }
        }
        f32x4 acc2 = (f32x4){0.f, 0.f, 0.f, 0.f};
#pragma unroll
        for (int kk = 0; kk < 3; kk++) {
            bf16x8 a2 = *(const bf16x8*)(hb + col * 104 + kk * 32 + quad * 8);
            acc2 = __builtin_amdgcn_mfma_f32_16x16x32_bf16(a2, w2f[kk], acc2, 0, 0, 0);
        }
        if (col < 4) {
#pragma unroll
            for (int rg = 0; rg < 4; rg++) {
                int P = tileBase + quad * 4 + rg;
                int rL = P / 44, k = P - rL * 44;
                if (k < 43) {
                    float mval = (float)smk16[rL][k];
                    slogb[rL][k * 4 + col] = f2bf((acc2[rg] + b2v) * mval);
                }
            }
        }
    }
    __syncthreads();

    if (t < 128) {
        int rL = t >> 2, c = t & 3;
        float mx = 0.f;
        for (int k = 0; k < K_; k++) mx = fmaxf(mx, bf2f(slogb[rL][k * 4 + c]));
        float den = 0.f;
        for (int k = 0; k < K_; k++) den += __expf(bf2f(slogb[rL][k * 4 + c]) - mx);
        float inv = 1.f / den;
        for (int k = 0; k < K_; k++)
            slogb[rL][k * 4 + c] = f2bf(__expf(bf2f(slogb[rL][k * 4 + c]) - mx) * inv);
    }
    __syncthreads();

    for (int p = t; p < 32 * 43; p += 256) {
        int rL = p / 43, k = p - rL * 43;
        int idxk = (k < 27) ? k : ((k < 35) ? (k - 27) : (k - 35));
        u16 mk = smk16[rL][k];
        ushort4 wout = make_ushort4(0, 0, 0, 0);
        if (mk) {
            wout.x = slogb[rL][idxk * 4 + 0];
            wout.y = slogb[rL][idxk * 4 + 1];
            wout.z = slogb[rL][idxk * 4 + 2];
            wout.w = slogb[rL][idxk * 4 + 3];
        }
        *(ushort4*)(wb + ((size_t)(r0 + rL) * 44 + k) * 4) = wout;
    }
}

// out[r][ch] = sum_k wb[r][k][cg] * V[src_k[r]][ch]
// MLP-batched 8-deep; V rows = row-scaled u8, 1 cache line (128B stride).
__global__ __launch_bounds__(256) void k_attn_gather(
    const u8* __restrict__ vq8, const u16* __restrict__ wb,
    const int* __restrict__ srcOf, float* __restrict__ out) {
    int idx = blockIdx.x * 256 + threadIdx.x;
    int r = idx / 24, c4 = idx - r * 24;
    if (r >= N_) return;
    int cg = c4 / 6;
    const u16* wrow = wb + (size_t)r * 176 + cg;
    float a0 = 0.f, a1 = 0.f, a2 = 0.f, a3 = 0.f;
    int sv[8]; float wv[8]; unsigned int vv[8]; float scv[8];
#pragma unroll 1
    for (int kb = 0; kb < 40; kb += 8) {
#pragma unroll
        for (int j = 0; j < 8; j++)
            sv[j] = srcOf[(size_t)(kb + j) * N_ + r];
#pragma unroll
        for (int j = 0; j < 8; j++)
            wv[j] = bf2f(wrow[(size_t)(kb + j) * 4]);
#pragma unroll
        for (int j = 0; j < 8; j++) {
            int sc = (sv[j] >= 0) ? sv[j] : 0;
            const u8* rp = vq8 + (size_t)sc * 128;
            vv[j] = *(const unsigned int*)(rp + c4 * 4);
            scv[j] = *(const float*)(rp + 96);
        }
#pragma unroll
        for (int j = 0; j < 8; j++) {
            float w = (sv[j] >= 0) ? wv[j] * scv[j] : 0.f;
            a0 += w * (float)(vv[j] & 0xffu);
            a1 += w * (float)((vv[j] >> 8) & 0xffu);
            a2 += w * (float)((vv[j] >> 16) & 0xffu);
            a3 += w * (float)((vv[j] >> 24) & 0xffu);
        }
    }
#pragma unroll
    for (int j = 0; j < 3; j++)
        sv[j] = srcOf[(size_t)(40 + j) * N_ + r];
#pragma unroll
    for (int j = 0; j < 3; j++)
        wv[j] = bf2f(wrow[(size_t)(40 + j) * 4]);
#pragma unroll
    for (int j = 0; j < 3; j++) {
        int sc = (sv[j] >= 0) ? sv[j] : 0;
        const u8* rp = vq8 + (size_t)sc * 128;
        vv[j] = *(const unsigned int*)(rp + c4 * 4);
        scv[j] = *(const float*)(rp + 96);
    }
#pragma unroll
    for (int j = 0; j < 3; j++) {
        float w = (sv[j] >= 0) ? wv[j] * scv[j] : 0.f;
        a0 += w * (float)(vv[j] & 0xffu);
        a1 += w * (float)((vv[j] >> 8) & 0xffu);
        a2 += w * (float)((vv[j] >> 16) & 0xffu);
        a3 += w * (float)((vv[j] >> 24) & 0xffu);
    }
    *(float4*)(out + (size_t)r * 96 + c4 * 4) = make_float4(a0, a1, a2, a3);
}

// ---------------------------------------------------------------------------
extern "C" void kernel_launch(void* const* d_in, const int* in_sizes, int n_in,
                              void* d_out, int out_size, void* d_ws, size_t ws_size,
                              hipStream_t stream) {
    const float* x      = (const float*)d_in[0];
    const float* coords = (const float*)d_in[1];
    const float* Wq1 = (const float*)d_in[2];
    const float* gq1 = (const float*)d_in[3];
    const float* bq1 = (const float*)d_in[4];
    const float* Wq2 = (const float*)d_in[5];
    const float* gq2 = (const float*)d_in[6];
    const float* bq2 = (const float*)d_in[7];
    const float* Wv  = (const float*)d_in[8];
    const float* gv  = (const float*)d_in[9];
    const float* bv  = (const float*)d_in[10];
    const float* Wp1 = (const float*)d_in[11];
    const float* gp1 = (const float*)d_in[12];
    const float* bp1 = (const float*)d_in[13];
    const float* Wp2 = (const float*)d_in[14];
    const float* gp2 = (const float*)d_in[15];
    const float* bp2 = (const float*)d_in[16];
    const float* W1  = (const float*)d_in[17];
    const float* b1  = (const float*)d_in[18];
    const float* W2  = (const float*)d_in[19];
    const float* b2  = (const float*)d_in[20];
    const float* g_out = (const float*)d_in[21];
    const float* b_out = (const float*)d_in[22];
    const int* kmaps = (const int*)d_in[23];
    float* out = (float*)d_out;

    // ---- workspace map (arena overlays; peak 92.35 MB < 98.8 budget) ----
    // Timeline: conv96 -> proj -> gather4 -> pe1s -> pe2b -> bnv8 -> logits
    //           -> gather -> final bn
    char* ws = (char*)d_ws;
    int*   srcOf  = (int*)ws;                     //  0 .. 17.2M        all
    float* rowAbs = (float*)(ws + 17200000);      // +400K              -> logits
    float* stats  = (float*)(ws + 17600000);      // +4,608             all
    u16*   w1b    = (u16*)(ws + 17604608);        // +6,144             -> logits
    u16*   w2b    = (u16*)(ws + 17610752);        // +3,072             -> logits
    u16*   Bimg   = (u16*)(ws + 17613824);        // +26,624            -> proj
    u16*   Wq1p   = (u16*)(ws + 17640448);        // +552,960           -> conv96
    u16*   Wvp    = (u16*)(ws + 18193408);        // +552,960           -> conv96
    char*  AR     = ws + 18746368;                // ---- arena ----
    u16*   xb     = (u16*)(AR + 0);               // 19.2M   -> conv96
    u16*   bufQb  = (u16*)(AR + 19200000);        // 19.2M   conv96 -> proj
    u16*   bufVb  = (u16*)(AR + 38400000);        // 19.2M   conv96 -> bnv8
    u16*   gbuf   = (u16*)(AR + 0);               // 21.6M   proj -> gather4 (ovl xb)
    float* qf     = (float*)(AR + 57600000);      // 1.6M    gather4 -> logits
    float* peb    = (float*)(AR + 59200000);      // 1.6M    pe2b -> bnv8
    u16*   pescr  = (u16*)(AR + 0);               // 19.2M   pe1s -> pe2b (ovl gbuf)
    u8*    vq8    = (u8*)(AR + 60800000);         // 12.8M   bnv8 -> gather
    u16*   wbuf   = (u16*)(AR + 0);               // 35.2M   logits -> gather (ovl pescr/bufQb)

    hipMemsetAsync(srcOf, 0xFF, (size_t)K_ * N_ * 4, stream);  // -1
    hipMemsetAsync(stats, 0, 6 * 192 * 4, stream);

    k_build_srcof<<<(K_ * M_ + 255) / 256, 256, 0, stream>>>(kmaps, srcOf);
    k_rowabs_cvt<<<N_ / 4, 256, 0, stream>>>(x, rowAbs, xb);
    k_wt96p<<<(KC_ * 9216 + 255) / 256, 256, 0, stream>>>(Wq1, Wq1p);
    k_wt96p<<<(KC_ * 9216 + 255) / 256, 256, 0, stream>>>(Wv, Wvp);
    k_wtB<<<52, 256, 0, stream>>>(Wq2, Bimg);
    k_w12b<<<12, 256, 0, stream>>>(W1, W2, w1b, w2b);

    const int cbD  = (N_ + 191) / 192;   // 521
    const int eb96 = N_ * 96 / 256;      // 37500
    const int eb24 = (N_ * 24) / 256;    // 9375
    const int eb4  = (N_ * 4 + 255) / 256;

    // P2: both convs (bf16 A-gather, proven) + their BN stats in one pass
    k_conv96_dual<<<cbD, 384, 0, stream>>>(xb, Wq1p, Wvp, srcOf, bufQb, bufVb,
                                           stats + 0 * 192, stats + 4 * 192);

    // P3/P4: q-branch: dense projection (bn inline) -> 8B gather -> stats
    // (qf stays RAW; bn+relu applied inline in attn_logits)
    k_proj<<<(N_ + 127) / 128, 256, 0, stream>>>(bufQb, stats + 0 * 192, gq1, bq1,
                                                 Bimg, gbuf);
    k_gather4<<<eb4, 256, 0, stream>>>(gbuf, srcOf, qf);
    k_bnstats4<<<512, 256, 0, stream>>>(qf, stats + 1 * 192);

    // P5: pe chain (pe1+stats fused; pe2 with inline bn of h1; peb stays RAW)
    k_pe1s<<<512, 192, 0, stream>>>(coords, Wp1, pescr, stats + 2 * 192);
    k_pe2b<<<eb4, 256, 0, stream>>>(pescr, stats + 2 * 192, gp1, bp1, Wp2, peb);
    k_bnstats4<<<512, 256, 0, stream>>>(peb, stats + 3 * 192);

    // P6: v-branch: bn+relu + relu(bn(peb)) -> row-scaled u8 vq8 (1-line rows)
    k_bnv8<<<N_ / 2, 192, 0, stream>>>(bufVb, stats + 4 * 192, gv, bv, peb,
                                       stats + 3 * 192, gp2, bp2, vq8);

    // P7/P8: attention (separate kernels; gather at full occupancy)
    k_attn_logits_mfma<<<N_ / 32, 256, 0, stream>>>(qf, srcOf, rowAbs, w1b, b1,
                                                    w2b, b2, stats + 1 * 192,
                                                    gq2, bq2, wbuf);
    k_attn_gather<<<eb24, 256, 0, stream>>>(vq8, wbuf, srcOf, out);

    // P9: out = relu(bn(out)) + x
    k_bnstats96<<<512, 192, 0, stream>>>(out, stats + 5 * 192);
    k_bnapply<96, 2><<<eb96, 256, 0, stream>>>(out, stats + 5 * 192, g_out, b_out, x);
}